// Round 19
// baseline (256.251 us; speedup 1.0000x reference)
//
#include <hip/hip_runtime.h>
#include <math.h>

#define BB 2
#define TT 1024
#define DD 1536
#define HH 12
#define TQK 768
#define TVv 1536
#define CQKV 3072
#define NQKVG 4608
#define EPSF 1e-6f
#define NBH (BB * HH)   // 24

typedef __attribute__((ext_vector_type(8))) _Float16 half8v;
typedef __attribute__((ext_vector_type(4))) float f32x4;

__device__ __forceinline__ float siluf(float x) { return x / (1.f + expf(-x)); }

__device__ __forceinline__ uint pk2h(float a, float b) {
  union { _Float16 h[2]; uint u; } p;
  p.h[0] = (_Float16)a; p.h[1] = (_Float16)b;
  return p.u;
}

// async global->LDS (GEMM staging)
__device__ __forceinline__ void gload16(const void* g, void* l) {
  __builtin_amdgcn_global_load_lds(
      (const __attribute__((address_space(1))) void*)g,
      (__attribute__((address_space(3))) void*)l, 16, 0, 0);
}

// ---------------------------------------------------------------------------
// fp16 MFMA GEMM, 2-phase pipelined (T3-minimum): stage tile k+1 via
// global_load_lds BEFORE computing tile k; ONE barrier per iteration, so the
// stage loads land under the MFMA phase. Double-buffered LDS (64KB).
// ---------------------------------------------------------------------------
__global__ __launch_bounds__(256) void gemm_f16(
    const ushort* __restrict__ X, const ushort* __restrict__ W,
    float* __restrict__ C1, float* __restrict__ C2,
    int M, int N, int K, int ldc1, int ldc2, int nsplit)
{
  __shared__ ushort Ah[2][128 * 64];
  __shared__ ushort Bh[2][128 * 64];
  const int tid  = threadIdx.x;
  const int lane = tid & 63;
  const int w    = tid >> 6;
  const int wr   = w >> 1, wc = w & 1;
  const int r0   = blockIdx.y * 128, c0 = blockIdx.x * 128;

  const int dr   = lane >> 3;
  const int slot = (lane & 7) ^ dr;

  f32x4 acc[4][4];
#pragma unroll
  for (int m = 0; m < 4; ++m)
#pragma unroll
    for (int n = 0; n < 4; ++n)
#pragma unroll
      for (int j = 0; j < 4; ++j) acc[m][n][j] = 0.f;

#define GSTAGE(B, K0) do { \
    _Pragma("unroll") \
    for (int j = 0; j < 4; ++j) { \
      const int row  = (w * 4 + j) * 8 + dr; \
      const size_t xo = (size_t)(r0 + row) * K + (K0) + slot * 8; \
      const size_t wo = (size_t)(c0 + row) * K + (K0) + slot * 8; \
      const int ldso = (w * 4 + j) * 512; \
      gload16(X + xo, &Ah[B][ldso]); \
      gload16(W + wo, &Bh[B][ldso]); \
    } \
  } while (0)

#define GCOMP(B) do { \
    _Pragma("unroll") \
    for (int kk = 0; kk < 2; ++kk) { \
      const int kc8 = kk * 4 + (lane >> 4); \
      const int sw  = (kc8 ^ (lane & 7)) << 3; \
      half8v a[4], b[4]; \
      _Pragma("unroll") \
      for (int m = 0; m < 4; ++m) \
        a[m] = *(const half8v*)(&Ah[B][(wr * 64 + m * 16 + (lane & 15)) * 64 + sw]); \
      _Pragma("unroll") \
      for (int n = 0; n < 4; ++n) \
        b[n] = *(const half8v*)(&Bh[B][(wc * 64 + n * 16 + (lane & 15)) * 64 + sw]); \
      _Pragma("unroll") \
      for (int m = 0; m < 4; ++m) \
        _Pragma("unroll") \
        for (int n = 0; n < 4; ++n) \
          acc[m][n] = __builtin_amdgcn_mfma_f32_16x16x32_f16(a[m], b[n], acc[m][n], 0, 0, 0); \
    } \
  } while (0)

  GSTAGE(0, 0);
  __syncthreads();
  int cur = 0;
  const int nks = K / 64;
  for (int ks = 0; ks < nks; ++ks) {
    if (ks + 1 < nks) GSTAGE(cur ^ 1, (ks + 1) * 64);   // loads fly under MFMA
    GCOMP(cur);
    __syncthreads();
    cur ^= 1;
  }
#undef GSTAGE
#undef GCOMP

  float* Cp; int ldc, cc0;
  if (c0 < nsplit) { Cp = C1; ldc = ldc1; cc0 = c0; }
  else             { Cp = C2; ldc = ldc2; cc0 = c0 - nsplit; }

  const int crow = (lane >> 4) * 4;
  const int ccol = lane & 15;
#pragma unroll
  for (int m = 0; m < 4; ++m)
#pragma unroll
    for (int j = 0; j < 4; ++j) {
      float* cp = Cp + (size_t)(r0 + wr * 64 + m * 16 + crow + j) * ldc + cc0 + wc * 64 + ccol;
#pragma unroll
      for (int n = 0; n < 4; ++n) cp[n * 16] = acc[m][n][j];
    }
}

// ---------------------------------------------------------------------------
// f32 -> fp16 casts.
// ---------------------------------------------------------------------------
__device__ __forceinline__ void cast8_store(const float* f, ushort* dst, size_t e)
{
  uint4 pk;
  pk.x = pk2h(f[0], f[1]); pk.y = pk2h(f[2], f[3]);
  pk.z = pk2h(f[4], f[5]); pk.w = pk2h(f[6], f[7]);
  *(uint4*)(dst + e) = pk;
}

__global__ void cast_f16_kernel(const float* __restrict__ src, ushort* __restrict__ dst)
{
  int cid = blockIdx.x * blockDim.x + threadIdx.x;
  size_t e = (size_t)cid * 8;
  float f[8];
  *(float4*)(f)     = *(const float4*)(src + e);
  *(float4*)(f + 4) = *(const float4*)(src + e + 4);
  cast8_store(f, dst, e);
}

__global__ void cast_w4_kernel(const float* __restrict__ wq, const float* __restrict__ wk,
                               const float* __restrict__ wv, const float* __restrict__ wg,
                               ushort* __restrict__ dst)
{
  int cid = blockIdx.x * blockDim.x + threadIdx.x;
  size_t e = (size_t)cid * 8;
  const float* src; size_t off;
  if (e < 1179648)      { src = wq; off = e; }
  else if (e < 2359296) { src = wk; off = e - 1179648; }
  else if (e < 4718592) { src = wv; off = e - 2359296; }
  else                  { src = wg; off = e - 4718592; }
  float f[8];
  *(float4*)(f)     = *(const float4*)(src + off);
  *(float4*)(f + 4) = *(const float4*)(src + off + 4);
  cast8_store(f, dst, e);
}

// ---------------------------------------------------------------------------
// Causal depthwise conv (K=4) + SiLU + fused L2-norm (q,k heads).
// ---------------------------------------------------------------------------
__global__ void conv_silu_kernel(
    const float* __restrict__ pre,
    const float* __restrict__ qw, const float* __restrict__ kw, const float* __restrict__ vw,
    float* __restrict__ qc, float* __restrict__ kc, float* __restrict__ vc)
{
  int idx = blockIdx.x * blockDim.x + threadIdx.x;
  int c  = idx % CQKV;
  int bt = idx / CQKV;
  int t  = bt % TT;
  int b  = bt / TT;

  const float* wp;
  if (c < TQK)          wp = qw + (size_t)c * 4;
  else if (c < 2 * TQK) wp = kw + (size_t)(c - TQK) * 4;
  else                  wp = vw + (size_t)(c - 2 * TQK) * 4;

  float s = 0.f;
#pragma unroll
  for (int j = 0; j < 4; ++j) {
    int ts = t - 3 + j;
    if (ts >= 0) s = fmaf(pre[(size_t)(b * TT + ts) * CQKV + c], wp[j], s);
  }
  s = siluf(s);

  if (c < 2 * TQK) {
    float ss = s * s;
#pragma unroll
    for (int m = 32; m >= 1; m >>= 1) ss += __shfl_xor(ss, m, 64);
    s = s / fmaxf(sqrtf(ss), EPSF);
  }

  if (c < TQK) {
    int h = c >> 6, d = c & 63;
    qc[((size_t)(b * HH + h) * TT + t) * 64 + d] = s;
  } else if (c < 2 * TQK) {
    int c2 = c - TQK; int h = c2 >> 6, d = c2 & 63;
    kc[((size_t)(b * HH + h) * TT + t) * 64 + d] = s;
  } else {
    int c2 = c - 2 * TQK; int h = c2 >> 7, d = c2 & 127;
    vc[((size_t)(b * HH + h) * TT + t) * 128 + d] = s;
  }
}

// ---------------------------------------------------------------------------
// Gating: block per row; writes interleaved (alpha,beta).
// ---------------------------------------------------------------------------
__global__ __launch_bounds__(256) void gate_kernel(
    const float* __restrict__ x, const float* __restrict__ w_a, const float* __restrict__ w_b,
    const float* __restrict__ A_log, const float* __restrict__ dt_bias,
    float* __restrict__ abi)
{
  const int m    = blockIdx.x;
  const int w    = threadIdx.x >> 6;
  const int lane = threadIdx.x & 63;
  const float* xr = x + (size_t)m * DD;
  float xv[24];
#pragma unroll
  for (int i = 0; i < 24; ++i) xv[i] = xr[lane + i * 64];
  const int b = m / TT, t = m % TT;
#pragma unroll
  for (int j = 0; j < 6; ++j) {
    int o = w * 6 + j;
    bool isA = o < HH;
    int h = isA ? o : o - HH;
    const float* wr = (isA ? w_a : w_b) + (size_t)h * DD;
    float s = 0.f;
#pragma unroll
    for (int i = 0; i < 24; ++i) s = fmaf(xv[i], wr[lane + i * 64], s);
#pragma unroll
    for (int mm = 32; mm >= 1; mm >>= 1) s += __shfl_xor(s, mm, 64);
    if (lane == 0) {
      size_t idx = ((size_t)(b * HH + h) * TT + t) * 2;
      if (isA) {
        float a  = s + dt_bias[h];
        float sp = (a > 20.f) ? a : log1pf(expf(a));
        abi[idx] = expf(-expf(A_log[h]) * sp);
      } else {
        abi[idx + 1] = 2.f / (1.f + expf(-s));
      }
    }
  }
}

// ---------------------------------------------------------------------------
// Shared 64x64 MFMA GEMM helper (verified): C = X @ Y^T.
// ---------------------------------------------------------------------------
__device__ __forceinline__ void gemm64(
    const _Float16* XB, int xstr, const _Float16* YB, int ystr,
    int wr, int wc, int lane, int ksteps, int kpad, f32x4 acc[2][2])
{
#pragma unroll
  for (int m = 0; m < 2; ++m)
#pragma unroll
    for (int n = 0; n < 2; ++n)
#pragma unroll
      for (int j = 0; j < 4; ++j) acc[m][n][j] = 0.f;
#pragma unroll 4
  for (int kk = 0; kk < ksteps; ++kk) {
    const int koff = kk * 32 + ((kk >> 1) ? kpad : 0) + (lane >> 4) * 8;
    half8v a[2], b[2];
#pragma unroll
    for (int m = 0; m < 2; ++m)
      a[m] = *(const half8v*)(XB + (wr * 32 + m * 16 + (lane & 15)) * xstr + koff);
#pragma unroll
    for (int n = 0; n < 2; ++n)
      b[n] = *(const half8v*)(YB + (wc * 32 + n * 16 + (lane & 15)) * ystr + koff);
#pragma unroll
    for (int m = 0; m < 2; ++m)
#pragma unroll
      for (int n = 0; n < 2; ++n)
        acc[m][n] = __builtin_amdgcn_mfma_f32_16x16x32_f16(a[m], b[n], acc[m][n], 0, 0, 0);
  }
}

// ---------------------------------------------------------------------------
// Scan phase A (chunk-parallel, 384 blocks): per chunk compute and store f16:
//   W = T diag(beta e^g) K   (4096)     P  = mask(e^dg Q K^T)  (4096)
//   Qg = e^g q               (4096)     KsT[d][t] = e^{gC-g_t} k (4096)
//   Z = T V                  (8192)     egCg[unit] = e^{gC}
// ---------------------------------------------------------------------------
__global__ __launch_bounds__(256) void scan_phaseA(
    const float* __restrict__ qc, const float* __restrict__ kc, const float* __restrict__ vc,
    const float* __restrict__ abi, _Float16* __restrict__ SA, float* __restrict__ egCg)
{
  __shared__ _Float16 Kf[64 * 72];      // aliased as Tf after ph2
  __shared__ _Float16 Qf[64 * 72];
  __shared__ _Float16 KbT[64 * 72];     // [d][i] = betg_i k_i[d]
  __shared__ _Float16 VT[128 * 72];     // [v][t]
  __shared__ float    Af[64 * 67];
  __shared__ float    Tg[64 * 67];
  __shared__ float    tmpf[1088];
  __shared__ float    g_s[64], bet_s[64], betg_s[64], eg_s[64], eKs_s[64];
  _Float16* Tf = Kf;

  const int unit = blockIdx.x;
  const int bh   = unit % NBH;
  const int c    = unit / NBH;
  const int c0   = c * 64;
  const int tid  = threadIdx.x;
  const int lane = tid & 63;
  const int w    = tid >> 6;
  const int wr   = w >> 1, wc = w & 1;

  _Float16* SAu = SA + (size_t)unit * 24576;

  // ph0: scalars [bar]
  if (tid < 64) {
    float2 ab = *(const float2*)(abi + ((size_t)bh * TT + c0 + tid) * 2);
    float gg = logf(ab.x);
#pragma unroll
    for (int off = 1; off < 64; off <<= 1) {
      float up = __shfl_up(gg, off, 64);
      if (tid >= off) gg += up;
    }
    float gC = __shfl(gg, 63, 64);
    g_s[tid]    = gg;
    bet_s[tid]  = ab.y;
    betg_s[tid] = ab.y * expf(gg);
    eg_s[tid]   = expf(gg);
    eKs_s[tid]  = expf(gC - gg);
    if (tid == 0) egCg[unit] = expf(gC);
  }
  __syncthreads();

  // ph1: build Kf, KbT, Qf, VT; store Qg, KsT scratch; zero Tg [bar]
  {
    const int t  = tid >> 2;
    const int dg = tid & 3;
    const float* krow = kc + ((size_t)bh * TT + c0 + t) * 64 + dg * 16;
    const float* qrow = qc + ((size_t)bh * TT + c0 + t) * 64 + dg * 16;
    const float bg = betg_s[t], egt = eg_s[t], ekt = eKs_s[t];
#pragma unroll
    for (int q4 = 0; q4 < 4; ++q4) {
      float4 kv = *(const float4*)(krow + q4 * 4);
      float4 qv = *(const float4*)(qrow + q4 * 4);
      const int d = dg * 16 + q4 * 4;
      const float kf[4] = {kv.x, kv.y, kv.z, kv.w};
      const float qf[4] = {qv.x, qv.y, qv.z, qv.w};
#pragma unroll
      for (int e = 0; e < 4; ++e) {
        Kf[t * 72 + d + e]        = (_Float16)kf[e];
        KbT[(d + e) * 72 + t]     = (_Float16)(kf[e] * bg);
        Qf[t * 72 + d + e]        = (_Float16)qf[e];
        SAu[8192 + t * 64 + d + e]  = (_Float16)(qf[e] * egt);   // Qg
        SAu[12288 + (d + e) * 64 + t] = (_Float16)(kf[e] * ekt); // KsT [d][t]
      }
    }
    const float* vrow = vc + ((size_t)bh * TT + c0 + t) * 128 + dg * 32;
#pragma unroll
    for (int q4 = 0; q4 < 8; ++q4) {
      float4 vv = *(const float4*)(vrow + q4 * 4);
      const int v = dg * 32 + q4 * 4;
      VT[(v + 0) * 72 + t] = (_Float16)vv.x;
      VT[(v + 1) * 72 + t] = (_Float16)vv.y;
      VT[(v + 2) * 72 + t] = (_Float16)vv.z;
      VT[(v + 3) * 72 + t] = (_Float16)vv.w;
    }
    for (int i = tid; i < 64 * 67; i += 256) Tg[i] = 0.f;
  }
  __syncthreads();

  // ph2: A = mask(beta e^dg K K^T) -> Af ; P = mask(e^dg Q K^T) -> scratch [bar]
  {
    f32x4 accA[2][2], accP[2][2];
    gemm64(Kf, 72, Kf, 72, wr, wc, lane, 2, 0, accA);
    gemm64(Qf, 72, Kf, 72, wr, wc, lane, 2, 0, accP);
#pragma unroll
    for (int m = 0; m < 2; ++m)
#pragma unroll
      for (int n = 0; n < 2; ++n)
#pragma unroll
        for (int j = 0; j < 4; ++j) {
          const int row = wr * 32 + m * 16 + (lane >> 4) * 4 + j;
          const int col = wc * 32 + n * 16 + (lane & 15);
          const float eg = expf(g_s[row] - g_s[col]);
          Af[row * 67 + col] = (col < row) ? bet_s[row] * eg * accA[m][n][j] : 0.f;
          SAu[4096 + row * 64 + col] =
              (col <= row) ? (_Float16)(eg * accP[m][n][j]) : (_Float16)0.f;
        }
  }
  __syncthreads();

  // ph3a: 4 diagonal 16x16 inverses into Tg [bar]
  if (lane < 16) {
    const int R = w * 16;
    Tg[R * 67 + R + lane] = (lane == 0) ? 1.f : 0.f;
    for (int t = 1; t < 16; ++t) {
      float s = 0.f;
      for (int i = 0; i < t; ++i)
        s = fmaf(Af[(R + t) * 67 + R + i], Tg[(R + i) * 67 + R + lane], s);
      Tg[(R + t) * 67 + R + lane] = ((lane == t) ? 1.f : 0.f) - s;
    }
  }
  __syncthreads();
  // ph3b-1 [bar]
  {
    const int r = (tid >> 4) & 15, cx = tid & 15;
#pragma unroll
    for (int p = 0; p < 2; ++p) {
      float s = 0.f;
      for (int i = 0; i < 16; ++i)
        s = fmaf(Af[(p * 32 + 16 + r) * 67 + p * 32 + i],
                 Tg[(p * 32 + i) * 67 + p * 32 + cx], s);
      tmpf[p * 272 + r * 17 + cx] = s;
    }
  }
  __syncthreads();
  // ph3b-2 [bar]
  {
    const int r = (tid >> 4) & 15, cx = tid & 15;
#pragma unroll
    for (int p = 0; p < 2; ++p) {
      float s = 0.f;
      for (int i = 0; i < 16; ++i)
        s = fmaf(Tg[(p * 32 + 16 + r) * 67 + p * 32 + 16 + i],
                 tmpf[p * 272 + i * 17 + cx], s);
      Tg[(p * 32 + 16 + r) * 67 + p * 32 + cx] = -s;
    }
  }
  __syncthreads();
  // ph3c-1 [bar]
  {
#pragma unroll
    for (int rep = 0; rep < 4; ++rep) {
      const int idx = tid + rep * 256;
      const int r = idx >> 5, cx = idx & 31;
      float s = 0.f;
      for (int i = 0; i < 32; ++i)
        s = fmaf(Af[(32 + r) * 67 + i], Tg[i * 67 + cx], s);
      tmpf[r * 33 + cx] = s;
    }
  }
  __syncthreads();
  // ph3c-2 [bar]
  {
#pragma unroll
    for (int rep = 0; rep < 4; ++rep) {
      const int idx = tid + rep * 256;
      const int r = idx >> 5, cx = idx & 31;
      float s = 0.f;
      for (int i = 0; i < 32; ++i)
        s = fmaf(Tg[(32 + r) * 67 + 32 + i], tmpf[i * 33 + cx], s);
      Tg[(32 + r) * 67 + cx] = -s;
    }
  }
  __syncthreads();

  // ph4: cast Tg -> Tf (aliases Kf; Kf dead after ph2) [bar]
  {
    const int t = tid >> 2, qg = tid & 3;
#pragma unroll
    for (int e = 0; e < 16; ++e) {
      const int i = qg * 16 + e;
      Tf[t * 72 + i] = (_Float16)Tg[t * 67 + i];
    }
  }
  __syncthreads();

  // ph5: W = T @ KbT^T -> scratch ; Z = T @ VT^T (two halves) -> scratch
  {
    f32x4 accW[2][2];
    gemm64(Tf, 72, KbT, 72, wr, wc, lane, 2, 0, accW);
#pragma unroll
    for (int m = 0; m < 2; ++m)
#pragma unroll
      for (int n = 0; n < 2; ++n)
#pragma unroll
        for (int j = 0; j < 4; ++j) {
          const int row = wr * 32 + m * 16 + (lane >> 4) * 4 + j;
          const int col = wc * 32 + n * 16 + (lane & 15);
          SAu[row * 64 + col] = (_Float16)accW[m][n][j];
        }
#pragma unroll
    for (int H = 0; H < 2; ++H) {
      f32x4 accZ[2][2];
      gemm64(Tf, 72, VT + H * 64 * 72, 72, wr, wc, lane, 2, 0, accZ);
#pragma unroll
      for (int m = 0; m < 2; ++m)
#pragma unroll
        for (int n = 0; n < 2; ++n)
#pragma unroll
          for (int j = 0; j < 4; ++j) {
            const int row = wr * 32 + m * 16 + (lane >> 4) * 4 + j;
            const int col = wc * 32 + n * 16 + (lane & 15);
            SAu[16384 + row * 128 + H * 64 + col] = (_Float16)accZ[m][n][j];
          }
    }
  }
}

// ---------------------------------------------------------------------------
// Scan phase B (serial over 16 chunks; 48 blocks = bh x 2 v-halves).
// R19: register prefetch of chunk c+1's scratch (10 uint4/thread, named
// arrays, static indices, pinned with sched_barrier) overlaps the 40KB load
// with b2+b3 compute -- removes load latency from the serial chain.
// ---------------------------------------------------------------------------
__global__ __launch_bounds__(256) void scan_phaseB(
    const _Float16* __restrict__ SA, const float* __restrict__ egCg,
    float* __restrict__ o)
{
  __shared__ float    Sf[64 * 65];      // S^T half [v][d] f32 (persistent)
  __shared__ _Float16 Wl[64 * 72];      // [t][d]
  __shared__ _Float16 KsTl[64 * 72];    // [d][t]
  __shared__ _Float16 Zl[64 * 72];      // [t][v-half]
  __shared__ _Float16 X2[64 * 144];     // [t][0:64]=Qg, [72:136]=P
  __shared__ _Float16 Y2[64 * 144];     // [v][0:64]=S0^T f16, [72:136]=U^T

  const int blk  = blockIdx.x;
  const int bh   = blk % NBH;
  const int H    = blk / NBH;           // 0..1 (v half)
  const int b    = bh / HH, h = bh % HH;
  const int tid  = threadIdx.x;
  const int lane = tid & 63;
  const int w    = tid >> 6;
  const int wr   = w >> 1, wc = w & 1;

  for (int i = tid; i < 64 * 65; i += 256) Sf[i] = 0.f;
  __syncthreads();

  uint4 pW[2], pP[2], pQ[2], pK[2], pZ[2];

#define PRELOAD(cc) do { \
    const ushort* bsrc = (const ushort*)(SA + (size_t)((cc) * NBH + bh) * 24576); \
    _Pragma("unroll") \
    for (int r = 0; r < 2; ++r) { \
      const int idx = tid + r * 256; \
      const int row = idx >> 3, c8 = idx & 7; \
      pW[r] = *(const uint4*)(bsrc + idx * 8); \
      pP[r] = *(const uint4*)(bsrc + 4096 + idx * 8); \
      pQ[r] = *(const uint4*)(bsrc + 8192 + idx * 8); \
      pK[r] = *(const uint4*)(bsrc + 12288 + idx * 8); \
      pZ[r] = *(const uint4*)(bsrc + 16384 + row * 128 + H * 64 + c8 * 8); \
    } \
  } while (0)

#define WRITELDS() do { \
    _Pragma("unroll") \
    for (int r = 0; r < 2; ++r) { \
      const int idx = tid + r * 256; \
      const int row = idx >> 3, c8 = idx & 7; \
      *(uint4*)((ushort*)Wl + row * 72 + c8 * 8)        = pW[r]; \
      *(uint4*)((ushort*)X2 + row * 144 + 72 + c8 * 8)  = pP[r]; \
      *(uint4*)((ushort*)X2 + row * 144 + c8 * 8)       = pQ[r]; \
      *(uint4*)((ushort*)KsTl + row * 72 + c8 * 8)      = pK[r]; \
      *(uint4*)((ushort*)Zl + row * 72 + c8 * 8)        = pZ[r]; \
    } \
  } while (0)

  PRELOAD(0);
  for (int c = 0; c < TT / 64; ++c) {
    const int c0 = c * 64;
    const float egC = egCg[(size_t)(c * NBH + bh)];

    // b1: LDS writes from prefetch regs; cast Sf -> Y2-left [bar]
    WRITELDS();
    {
      const int v = tid >> 2, ds = tid & 3;
#pragma unroll
      for (int e = 0; e < 16; ++e)
        Y2[v * 144 + ds * 16 + e] = (_Float16)Sf[v * 65 + ds * 16 + e];
    }
    __syncthreads();
    if (c + 1 < TT / 64) PRELOAD(c + 1);     // in flight over b2+b3
    __builtin_amdgcn_sched_barrier(0);

    // b2: U = Z - W @ S0 -> Y2-right [bar]
    {
      f32x4 accU[2][2];
      gemm64(Wl, 72, Y2, 144, wr, wc, lane, 2, 0, accU);
#pragma unroll
      for (int m = 0; m < 2; ++m)
#pragma unroll
        for (int n = 0; n < 2; ++n)
#pragma unroll
          for (int j = 0; j < 4; ++j) {
            const int row = wr * 32 + m * 16 + (lane >> 4) * 4 + j;  // t
            const int col = wc * 32 + n * 16 + (lane & 15);          // v
            const float uval = (float)Zl[row * 72 + col] - accU[m][n][j];
            Y2[col * 144 + 72 + row] = (_Float16)uval;
          }
    }
    __syncthreads();

    // b3: S = egC*S + KsT@U ; O = [Qg|P]@[S0^T|U^T]^T -> o [bar]
    {
      f32x4 accS[2][2], accO[2][2];
      gemm64(KsTl, 72, Y2 + 72, 144, wr, wc, lane, 2, 0, accS);
      gemm64(X2, 144, Y2, 144, wr, wc, lane, 4, 8, accO);
#pragma unroll
      for (int m = 0; m < 2; ++m)
#pragma unroll
        for (int n = 0; n < 2; ++n)
#pragma unroll
          for (int j = 0; j < 4; ++j) {
            const int row = wr * 32 + m * 16 + (lane >> 4) * 4 + j;  // d (S) / t (O)
            const int col = wc * 32 + n * 16 + (lane & 15);          // v
            Sf[col * 65 + row] = egC * Sf[col * 65 + row] + accS[m][n][j];
            o[(((size_t)b * TT + c0 + row) * HH + h) * 128 + H * 64 + col] = accO[m][n][j];
          }
    }
    __syncthreads();
  }
#undef PRELOAD
#undef WRITELDS
}

// ---------------------------------------------------------------------------
// RMS norm over 128 + SiLU gate; emits fp16 for the final GEMM.
// ---------------------------------------------------------------------------
__global__ void rmsgate_kernel(const float* __restrict__ o, const float* __restrict__ gpre,
                               ushort* __restrict__ gof)
{
  int gid  = blockIdx.x * blockDim.x + threadIdx.x;
  int wid  = gid >> 6;
  int lane = threadIdx.x & 63;
  if (wid >= BB * TT * HH) return;
  int h = wid % HH;
  int m = wid / HH;
  const float* orow = o + (size_t)wid * 128;
  float2 ov = *(const float2*)(orow + lane * 2);
  float ss = ov.x * ov.x + ov.y * ov.y;
#pragma unroll
  for (int mm = 32; mm >= 1; mm >>= 1) ss += __shfl_xor(ss, mm, 64);
  float scale = rsqrtf(ss * (1.f / 128.f) + EPSF);
  const float* gr = gpre + (size_t)m * TVv + h * 128 + lane * 2;
  float o0 = ov.x * scale * siluf(gr[0]);
  float o1 = ov.y * scale * siluf(gr[1]);
  *(uint*)(gof + (size_t)m * TVv + h * 128 + lane * 2) = pk2h(o0, o1);
}

// ---------------------------------------------------------------------------
extern "C" void kernel_launch(void* const* d_in, const int* in_sizes, int n_in,
                              void* d_out, int out_size, void* d_ws, size_t ws_size,
                              hipStream_t stream) {
  (void)in_sizes; (void)n_in; (void)out_size; (void)ws_size;
  const float* x       = (const float*)d_in[0];
  const float* w_q     = (const float*)d_in[1];
  const float* w_k     = (const float*)d_in[2];
  const float* w_v     = (const float*)d_in[3];
  const float* w_a     = (const float*)d_in[4];
  const float* w_b     = (const float*)d_in[5];
  const float* w_g     = (const float*)d_in[6];
  const float* w_out   = (const float*)d_in[7];
  const float* A_log   = (const float*)d_in[8];
  const float* dt_bias = (const float*)d_in[9];
  const float* qcw     = (const float*)d_in[10];
  const float* kcw     = (const float*)d_in[11];
  const float* vcw     = (const float*)d_in[12];

  // Workspace (63.11 MB proven footprint), time-multiplexed:
  //  ws[0..6291456)        : qkv_pre -> SA scratch + egCg -> gof
  //  ws[6291456..9437184)  : g_pre
  //  ws[9437184..15728640) : Cu: xf+wcat -> qc/kc/vc -> o + woutf
  //  ws[15728640..15777792): abi
  float* ws      = (float*)d_ws;
  float* qkv_pre = ws;
  float* g_pre   = ws + 6291456;
  float* Cu      = ws + 9437184;
  float* abi     = ws + 15728640;

  ushort* xf    = (ushort*)Cu;
  ushort* wcat  = (ushort*)(Cu + 1572864);

  float* qc = Cu;
  float* kc = Cu + 1572864;
  float* vc = Cu + 3145728;

  _Float16* SA   = (_Float16*)ws;              // 384 units * 24576 f16
  float*    egCg = ws + 4718592;               // 384 floats

  float*  o     = Cu;                          // overwrites dead qc/kc
  ushort* woutf = (ushort*)(Cu + 3145728);     // overwrites dead vc
  ushort* gof   = (ushort*)ws;                 // overwrites dead SA scratch

  const int M = BB * TT;  // 2048
  dim3 blk(256);

  // 1) fp16 casts
  cast_f16_kernel<<<1536, blk, 0, stream>>>(x, xf);
  cast_w4_kernel<<<3456, blk, 0, stream>>>(w_q, w_k, w_v, w_g, wcat);

  // 2) fused qkv+g projection (2-phase pipelined)
  gemm_f16<<<dim3(NQKVG / 128, M / 128), blk, 0, stream>>>(
      xf, wcat, qkv_pre, g_pre, M, NQKVG, DD, CQKV, TVv, CQKV);

  // 3) gating coefficients
  gate_kernel<<<M, blk, 0, stream>>>(x, w_a, w_b, A_log, dt_bias, abi);

  // 4) conv + SiLU + L2 norm
  conv_silu_kernel<<<24576, blk, 0, stream>>>(qkv_pre, qcw, kcw, vcw, qc, kc, vc);

  // 5) scan: chunk-parallel phase A, prefetching serial phase B
  scan_phaseA<<<16 * NBH, blk, 0, stream>>>(qc, kc, vc, abi, SA, egCg);
  scan_phaseB<<<2 * NBH, blk, 0, stream>>>(SA, egCg, o);

  // 6) cast w_out (into dead vc region)
  cast_f16_kernel<<<1152, blk, 0, stream>>>(w_out, woutf);

  // 7) RMS norm + SiLU gate (gof overwrites dead SA scratch)
  rmsgate_kernel<<<6144, blk, 0, stream>>>(o, g_pre, gof);

  // 8) output projection (2-phase pipelined)
  gemm_f16<<<dim3(TVv / 128, M / 128), blk, 0, stream>>>(
      gof, woutf, (float*)d_out, (float*)d_out, M, TVv, DD, TVv, TVv, TVv);
}

// Round 20
// 231.745 us; speedup vs baseline: 1.1057x; 1.1057x over previous
//
#include <hip/hip_runtime.h>
#include <math.h>

#define BB 2
#define TT 1024
#define DD 1536
#define HH 12
#define TQK 768
#define TVv 1536
#define CQKV 3072
#define NQKVG 4608
#define EPSF 1e-6f
#define NBH (BB * HH)   // 24

typedef __attribute__((ext_vector_type(8))) _Float16 half8v;
typedef __attribute__((ext_vector_type(4))) float f32x4;

__device__ __forceinline__ float siluf(float x) { return x / (1.f + expf(-x)); }

__device__ __forceinline__ uint pk2h(float a, float b) {
  union { _Float16 h[2]; uint u; } p;
  p.h[0] = (_Float16)a; p.h[1] = (_Float16)b;
  return p.u;
}

// async global->LDS (GEMM staging)
__device__ __forceinline__ void gload16(const void* g, void* l) {
  __builtin_amdgcn_global_load_lds(
      (const __attribute__((address_space(1))) void*)g,
      (__attribute__((address_space(3))) void*)l, 16, 0, 0);
}

// ---------------------------------------------------------------------------
// fp16 MFMA GEMM, 2-phase pipelined (kept from R19 — measured <= 62.8us vs
// 64.5 single-buffered): stage tile k+1 via global_load_lds BEFORE computing
// tile k; one barrier per iteration. Double-buffered LDS (64KB).
// ---------------------------------------------------------------------------
__global__ __launch_bounds__(256) void gemm_f16(
    const ushort* __restrict__ X, const ushort* __restrict__ W,
    float* __restrict__ C1, float* __restrict__ C2,
    int M, int N, int K, int ldc1, int ldc2, int nsplit)
{
  __shared__ ushort Ah[2][128 * 64];
  __shared__ ushort Bh[2][128 * 64];
  const int tid  = threadIdx.x;
  const int lane = tid & 63;
  const int w    = tid >> 6;
  const int wr   = w >> 1, wc = w & 1;
  const int r0   = blockIdx.y * 128, c0 = blockIdx.x * 128;

  const int dr   = lane >> 3;
  const int slot = (lane & 7) ^ dr;

  f32x4 acc[4][4];
#pragma unroll
  for (int m = 0; m < 4; ++m)
#pragma unroll
    for (int n = 0; n < 4; ++n)
#pragma unroll
      for (int j = 0; j < 4; ++j) acc[m][n][j] = 0.f;

#define GSTAGE(B, K0) do { \
    _Pragma("unroll") \
    for (int j = 0; j < 4; ++j) { \
      const int row  = (w * 4 + j) * 8 + dr; \
      const size_t xo = (size_t)(r0 + row) * K + (K0) + slot * 8; \
      const size_t wo = (size_t)(c0 + row) * K + (K0) + slot * 8; \
      const int ldso = (w * 4 + j) * 512; \
      gload16(X + xo, &Ah[B][ldso]); \
      gload16(W + wo, &Bh[B][ldso]); \
    } \
  } while (0)

#define GCOMP(B) do { \
    _Pragma("unroll") \
    for (int kk = 0; kk < 2; ++kk) { \
      const int kc8 = kk * 4 + (lane >> 4); \
      const int sw  = (kc8 ^ (lane & 7)) << 3; \
      half8v a[4], b[4]; \
      _Pragma("unroll") \
      for (int m = 0; m < 4; ++m) \
        a[m] = *(const half8v*)(&Ah[B][(wr * 64 + m * 16 + (lane & 15)) * 64 + sw]); \
      _Pragma("unroll") \
      for (int n = 0; n < 4; ++n) \
        b[n] = *(const half8v*)(&Bh[B][(wc * 64 + n * 16 + (lane & 15)) * 64 + sw]); \
      _Pragma("unroll") \
      for (int m = 0; m < 4; ++m) \
        _Pragma("unroll") \
        for (int n = 0; n < 4; ++n) \
          acc[m][n] = __builtin_amdgcn_mfma_f32_16x16x32_f16(a[m], b[n], acc[m][n], 0, 0, 0); \
    } \
  } while (0)

  GSTAGE(0, 0);
  __syncthreads();
  int cur = 0;
  const int nks = K / 64;
  for (int ks = 0; ks < nks; ++ks) {
    if (ks + 1 < nks) GSTAGE(cur ^ 1, (ks + 1) * 64);   // loads fly under MFMA
    GCOMP(cur);
    __syncthreads();
    cur ^= 1;
  }
#undef GSTAGE
#undef GCOMP

  float* Cp; int ldc, cc0;
  if (c0 < nsplit) { Cp = C1; ldc = ldc1; cc0 = c0; }
  else             { Cp = C2; ldc = ldc2; cc0 = c0 - nsplit; }

  const int crow = (lane >> 4) * 4;
  const int ccol = lane & 15;
#pragma unroll
  for (int m = 0; m < 4; ++m)
#pragma unroll
    for (int j = 0; j < 4; ++j) {
      float* cp = Cp + (size_t)(r0 + wr * 64 + m * 16 + crow + j) * ldc + cc0 + wc * 64 + ccol;
#pragma unroll
      for (int n = 0; n < 4; ++n) cp[n * 16] = acc[m][n][j];
    }
}

// ---------------------------------------------------------------------------
// f32 -> fp16 casts.
// ---------------------------------------------------------------------------
__device__ __forceinline__ void cast8_store(const float* f, ushort* dst, size_t e)
{
  uint4 pk;
  pk.x = pk2h(f[0], f[1]); pk.y = pk2h(f[2], f[3]);
  pk.z = pk2h(f[4], f[5]); pk.w = pk2h(f[6], f[7]);
  *(uint4*)(dst + e) = pk;
}

__global__ void cast_f16_kernel(const float* __restrict__ src, ushort* __restrict__ dst)
{
  int cid = blockIdx.x * blockDim.x + threadIdx.x;
  size_t e = (size_t)cid * 8;
  float f[8];
  *(float4*)(f)     = *(const float4*)(src + e);
  *(float4*)(f + 4) = *(const float4*)(src + e + 4);
  cast8_store(f, dst, e);
}

__global__ void cast_w4_kernel(const float* __restrict__ wq, const float* __restrict__ wk,
                               const float* __restrict__ wv, const float* __restrict__ wg,
                               ushort* __restrict__ dst)
{
  int cid = blockIdx.x * blockDim.x + threadIdx.x;
  size_t e = (size_t)cid * 8;
  const float* src; size_t off;
  if (e < 1179648)      { src = wq; off = e; }
  else if (e < 2359296) { src = wk; off = e - 1179648; }
  else if (e < 4718592) { src = wv; off = e - 2359296; }
  else                  { src = wg; off = e - 4718592; }
  float f[8];
  *(float4*)(f)     = *(const float4*)(src + off);
  *(float4*)(f + 4) = *(const float4*)(src + off + 4);
  cast8_store(f, dst, e);
}

// ---------------------------------------------------------------------------
// Causal depthwise conv (K=4) + SiLU + fused L2-norm (q,k heads).
// ---------------------------------------------------------------------------
__global__ void conv_silu_kernel(
    const float* __restrict__ pre,
    const float* __restrict__ qw, const float* __restrict__ kw, const float* __restrict__ vw,
    float* __restrict__ qc, float* __restrict__ kc, float* __restrict__ vc)
{
  int idx = blockIdx.x * blockDim.x + threadIdx.x;
  int c  = idx % CQKV;
  int bt = idx / CQKV;
  int t  = bt % TT;
  int b  = bt / TT;

  const float* wp;
  if (c < TQK)          wp = qw + (size_t)c * 4;
  else if (c < 2 * TQK) wp = kw + (size_t)(c - TQK) * 4;
  else                  wp = vw + (size_t)(c - 2 * TQK) * 4;

  float s = 0.f;
#pragma unroll
  for (int j = 0; j < 4; ++j) {
    int ts = t - 3 + j;
    if (ts >= 0) s = fmaf(pre[(size_t)(b * TT + ts) * CQKV + c], wp[j], s);
  }
  s = siluf(s);

  if (c < 2 * TQK) {
    float ss = s * s;
#pragma unroll
    for (int m = 32; m >= 1; m >>= 1) ss += __shfl_xor(ss, m, 64);
    s = s / fmaxf(sqrtf(ss), EPSF);
  }

  if (c < TQK) {
    int h = c >> 6, d = c & 63;
    qc[((size_t)(b * HH + h) * TT + t) * 64 + d] = s;
  } else if (c < 2 * TQK) {
    int c2 = c - TQK; int h = c2 >> 6, d = c2 & 63;
    kc[((size_t)(b * HH + h) * TT + t) * 64 + d] = s;
  } else {
    int c2 = c - 2 * TQK; int h = c2 >> 7, d = c2 & 127;
    vc[((size_t)(b * HH + h) * TT + t) * 128 + d] = s;
  }
}

// ---------------------------------------------------------------------------
// Gating: block per row; writes interleaved (alpha,beta).
// ---------------------------------------------------------------------------
__global__ __launch_bounds__(256) void gate_kernel(
    const float* __restrict__ x, const float* __restrict__ w_a, const float* __restrict__ w_b,
    const float* __restrict__ A_log, const float* __restrict__ dt_bias,
    float* __restrict__ abi)
{
  const int m    = blockIdx.x;
  const int w    = threadIdx.x >> 6;
  const int lane = threadIdx.x & 63;
  const float* xr = x + (size_t)m * DD;
  float xv[24];
#pragma unroll
  for (int i = 0; i < 24; ++i) xv[i] = xr[lane + i * 64];
  const int b = m / TT, t = m % TT;
#pragma unroll
  for (int j = 0; j < 6; ++j) {
    int o = w * 6 + j;
    bool isA = o < HH;
    int h = isA ? o : o - HH;
    const float* wr = (isA ? w_a : w_b) + (size_t)h * DD;
    float s = 0.f;
#pragma unroll
    for (int i = 0; i < 24; ++i) s = fmaf(xv[i], wr[lane + i * 64], s);
#pragma unroll
    for (int mm = 32; mm >= 1; mm >>= 1) s += __shfl_xor(s, mm, 64);
    if (lane == 0) {
      size_t idx = ((size_t)(b * HH + h) * TT + t) * 2;
      if (isA) {
        float a  = s + dt_bias[h];
        float sp = (a > 20.f) ? a : log1pf(expf(a));
        abi[idx] = expf(-expf(A_log[h]) * sp);
      } else {
        abi[idx + 1] = 2.f / (1.f + expf(-s));
      }
    }
  }
}

// ---------------------------------------------------------------------------
// Shared 64x64 MFMA GEMM helper (verified): C = X @ Y^T.
// ---------------------------------------------------------------------------
__device__ __forceinline__ void gemm64(
    const _Float16* XB, int xstr, const _Float16* YB, int ystr,
    int wr, int wc, int lane, int ksteps, int kpad, f32x4 acc[2][2])
{
#pragma unroll
  for (int m = 0; m < 2; ++m)
#pragma unroll
    for (int n = 0; n < 2; ++n)
#pragma unroll
      for (int j = 0; j < 4; ++j) acc[m][n][j] = 0.f;
#pragma unroll 4
  for (int kk = 0; kk < ksteps; ++kk) {
    const int koff = kk * 32 + ((kk >> 1) ? kpad : 0) + (lane >> 4) * 8;
    half8v a[2], b[2];
#pragma unroll
    for (int m = 0; m < 2; ++m)
      a[m] = *(const half8v*)(XB + (wr * 32 + m * 16 + (lane & 15)) * xstr + koff);
#pragma unroll
    for (int n = 0; n < 2; ++n)
      b[n] = *(const half8v*)(YB + (wc * 32 + n * 16 + (lane & 15)) * ystr + koff);
#pragma unroll
    for (int m = 0; m < 2; ++m)
#pragma unroll
      for (int n = 0; n < 2; ++n)
        acc[m][n] = __builtin_amdgcn_mfma_f32_16x16x32_f16(a[m], b[n], acc[m][n], 0, 0, 0);
  }
}

// ---------------------------------------------------------------------------
// Scan phase A (chunk-parallel, 384 blocks): per chunk compute and store f16:
//   W = T diag(beta e^g) K   (4096)     P  = mask(e^dg Q K^T)  (4096)
//   Qg = e^g q               (4096)     KsT[d][t] = e^{gC-g_t} k (4096)
//   Z = T V                  (8192)     egCg[unit] = e^{gC}
// ---------------------------------------------------------------------------
__global__ __launch_bounds__(256) void scan_phaseA(
    const float* __restrict__ qc, const float* __restrict__ kc, const float* __restrict__ vc,
    const float* __restrict__ abi, _Float16* __restrict__ SA, float* __restrict__ egCg)
{
  __shared__ _Float16 Kf[64 * 72];      // aliased as Tf after ph2
  __shared__ _Float16 Qf[64 * 72];
  __shared__ _Float16 KbT[64 * 72];     // [d][i] = betg_i k_i[d]
  __shared__ _Float16 VT[128 * 72];     // [v][t]
  __shared__ float    Af[64 * 67];
  __shared__ float    Tg[64 * 67];
  __shared__ float    tmpf[1088];
  __shared__ float    g_s[64], bet_s[64], betg_s[64], eg_s[64], eKs_s[64];
  _Float16* Tf = Kf;

  const int unit = blockIdx.x;
  const int bh   = unit % NBH;
  const int c    = unit / NBH;
  const int c0   = c * 64;
  const int tid  = threadIdx.x;
  const int lane = tid & 63;
  const int w    = tid >> 6;
  const int wr   = w >> 1, wc = w & 1;

  _Float16* SAu = SA + (size_t)unit * 24576;

  // ph0: scalars [bar]
  if (tid < 64) {
    float2 ab = *(const float2*)(abi + ((size_t)bh * TT + c0 + tid) * 2);
    float gg = logf(ab.x);
#pragma unroll
    for (int off = 1; off < 64; off <<= 1) {
      float up = __shfl_up(gg, off, 64);
      if (tid >= off) gg += up;
    }
    float gC = __shfl(gg, 63, 64);
    g_s[tid]    = gg;
    bet_s[tid]  = ab.y;
    betg_s[tid] = ab.y * expf(gg);
    eg_s[tid]   = expf(gg);
    eKs_s[tid]  = expf(gC - gg);
    if (tid == 0) egCg[unit] = expf(gC);
  }
  __syncthreads();

  // ph1: build Kf, KbT, Qf, VT; store Qg, KsT scratch; zero Tg [bar]
  {
    const int t  = tid >> 2;
    const int dg = tid & 3;
    const float* krow = kc + ((size_t)bh * TT + c0 + t) * 64 + dg * 16;
    const float* qrow = qc + ((size_t)bh * TT + c0 + t) * 64 + dg * 16;
    const float bg = betg_s[t], egt = eg_s[t], ekt = eKs_s[t];
#pragma unroll
    for (int q4 = 0; q4 < 4; ++q4) {
      float4 kv = *(const float4*)(krow + q4 * 4);
      float4 qv = *(const float4*)(qrow + q4 * 4);
      const int d = dg * 16 + q4 * 4;
      const float kf[4] = {kv.x, kv.y, kv.z, kv.w};
      const float qf[4] = {qv.x, qv.y, qv.z, qv.w};
#pragma unroll
      for (int e = 0; e < 4; ++e) {
        Kf[t * 72 + d + e]        = (_Float16)kf[e];
        KbT[(d + e) * 72 + t]     = (_Float16)(kf[e] * bg);
        Qf[t * 72 + d + e]        = (_Float16)qf[e];
        SAu[8192 + t * 64 + d + e]  = (_Float16)(qf[e] * egt);   // Qg
        SAu[12288 + (d + e) * 64 + t] = (_Float16)(kf[e] * ekt); // KsT [d][t]
      }
    }
    const float* vrow = vc + ((size_t)bh * TT + c0 + t) * 128 + dg * 32;
#pragma unroll
    for (int q4 = 0; q4 < 8; ++q4) {
      float4 vv = *(const float4*)(vrow + q4 * 4);
      const int v = dg * 32 + q4 * 4;
      VT[(v + 0) * 72 + t] = (_Float16)vv.x;
      VT[(v + 1) * 72 + t] = (_Float16)vv.y;
      VT[(v + 2) * 72 + t] = (_Float16)vv.z;
      VT[(v + 3) * 72 + t] = (_Float16)vv.w;
    }
    for (int i = tid; i < 64 * 67; i += 256) Tg[i] = 0.f;
  }
  __syncthreads();

  // ph2: A = mask(beta e^dg K K^T) -> Af ; P = mask(e^dg Q K^T) -> scratch [bar]
  {
    f32x4 accA[2][2], accP[2][2];
    gemm64(Kf, 72, Kf, 72, wr, wc, lane, 2, 0, accA);
    gemm64(Qf, 72, Kf, 72, wr, wc, lane, 2, 0, accP);
#pragma unroll
    for (int m = 0; m < 2; ++m)
#pragma unroll
      for (int n = 0; n < 2; ++n)
#pragma unroll
        for (int j = 0; j < 4; ++j) {
          const int row = wr * 32 + m * 16 + (lane >> 4) * 4 + j;
          const int col = wc * 32 + n * 16 + (lane & 15);
          const float eg = expf(g_s[row] - g_s[col]);
          Af[row * 67 + col] = (col < row) ? bet_s[row] * eg * accA[m][n][j] : 0.f;
          SAu[4096 + row * 64 + col] =
              (col <= row) ? (_Float16)(eg * accP[m][n][j]) : (_Float16)0.f;
        }
  }
  __syncthreads();

  // ph3a: 4 diagonal 16x16 inverses into Tg [bar]
  if (lane < 16) {
    const int R = w * 16;
    Tg[R * 67 + R + lane] = (lane == 0) ? 1.f : 0.f;
    for (int t = 1; t < 16; ++t) {
      float s = 0.f;
      for (int i = 0; i < t; ++i)
        s = fmaf(Af[(R + t) * 67 + R + i], Tg[(R + i) * 67 + R + lane], s);
      Tg[(R + t) * 67 + R + lane] = ((lane == t) ? 1.f : 0.f) - s;
    }
  }
  __syncthreads();
  // ph3b-1 [bar]
  {
    const int r = (tid >> 4) & 15, cx = tid & 15;
#pragma unroll
    for (int p = 0; p < 2; ++p) {
      float s = 0.f;
      for (int i = 0; i < 16; ++i)
        s = fmaf(Af[(p * 32 + 16 + r) * 67 + p * 32 + i],
                 Tg[(p * 32 + i) * 67 + p * 32 + cx], s);
      tmpf[p * 272 + r * 17 + cx] = s;
    }
  }
  __syncthreads();
  // ph3b-2 [bar]
  {
    const int r = (tid >> 4) & 15, cx = tid & 15;
#pragma unroll
    for (int p = 0; p < 2; ++p) {
      float s = 0.f;
      for (int i = 0; i < 16; ++i)
        s = fmaf(Tg[(p * 32 + 16 + r) * 67 + p * 32 + 16 + i],
                 tmpf[p * 272 + i * 17 + cx], s);
      Tg[(p * 32 + 16 + r) * 67 + p * 32 + cx] = -s;
    }
  }
  __syncthreads();
  // ph3c-1 [bar]
  {
#pragma unroll
    for (int rep = 0; rep < 4; ++rep) {
      const int idx = tid + rep * 256;
      const int r = idx >> 5, cx = idx & 31;
      float s = 0.f;
      for (int i = 0; i < 32; ++i)
        s = fmaf(Af[(32 + r) * 67 + i], Tg[i * 67 + cx], s);
      tmpf[r * 33 + cx] = s;
    }
  }
  __syncthreads();
  // ph3c-2 [bar]
  {
#pragma unroll
    for (int rep = 0; rep < 4; ++rep) {
      const int idx = tid + rep * 256;
      const int r = idx >> 5, cx = idx & 31;
      float s = 0.f;
      for (int i = 0; i < 32; ++i)
        s = fmaf(Tg[(32 + r) * 67 + 32 + i], tmpf[i * 33 + cx], s);
      Tg[(32 + r) * 67 + cx] = -s;
    }
  }
  __syncthreads();

  // ph4: cast Tg -> Tf (aliases Kf; Kf dead after ph2) [bar]
  {
    const int t = tid >> 2, qg = tid & 3;
#pragma unroll
    for (int e = 0; e < 16; ++e) {
      const int i = qg * 16 + e;
      Tf[t * 72 + i] = (_Float16)Tg[t * 67 + i];
    }
  }
  __syncthreads();

  // ph5: W = T @ KbT^T -> scratch ; Z = T @ VT^T (two halves) -> scratch
  {
    f32x4 accW[2][2];
    gemm64(Tf, 72, KbT, 72, wr, wc, lane, 2, 0, accW);
#pragma unroll
    for (int m = 0; m < 2; ++m)
#pragma unroll
      for (int n = 0; n < 2; ++n)
#pragma unroll
        for (int j = 0; j < 4; ++j) {
          const int row = wr * 32 + m * 16 + (lane >> 4) * 4 + j;
          const int col = wc * 32 + n * 16 + (lane & 15);
          SAu[row * 64 + col] = (_Float16)accW[m][n][j];
        }
#pragma unroll
    for (int H = 0; H < 2; ++H) {
      f32x4 accZ[2][2];
      gemm64(Tf, 72, VT + H * 64 * 72, 72, wr, wc, lane, 2, 0, accZ);
#pragma unroll
      for (int m = 0; m < 2; ++m)
#pragma unroll
        for (int n = 0; n < 2; ++n)
#pragma unroll
          for (int j = 0; j < 4; ++j) {
            const int row = wr * 32 + m * 16 + (lane >> 4) * 4 + j;
            const int col = wc * 32 + n * 16 + (lane & 15);
            SAu[16384 + row * 128 + H * 64 + col] = (_Float16)accZ[m][n][j];
          }
    }
  }
}

// ---------------------------------------------------------------------------
// Scan phase B (serial over 16 chunks; 48 blocks = bh x 2 v-halves): pure
// scratch consumer (R18-proven form — inline loads in b1; the R19 register
// prefetch collapsed in regalloc, VGPR 88, and regressed).
// ---------------------------------------------------------------------------
__global__ __launch_bounds__(256) void scan_phaseB(
    const _Float16* __restrict__ SA, const float* __restrict__ egCg,
    float* __restrict__ o)
{
  __shared__ float    Sf[64 * 65];      // S^T half [v][d] f32 (persistent)
  __shared__ _Float16 Wl[64 * 72];      // [t][d]
  __shared__ _Float16 KsTl[64 * 72];    // [d][t]
  __shared__ _Float16 Zl[64 * 72];      // [t][v-half]
  __shared__ _Float16 X2[64 * 144];     // [t][0:64]=Qg, [72:136]=P
  __shared__ _Float16 Y2[64 * 144];     // [v][0:64]=S0^T f16, [72:136]=U^T

  const int blk  = blockIdx.x;
  const int bh   = blk % NBH;
  const int H    = blk / NBH;           // 0..1 (v half)
  const int b    = bh / HH, h = bh % HH;
  const int tid  = threadIdx.x;
  const int lane = tid & 63;
  const int w    = tid >> 6;
  const int wr   = w >> 1, wc = w & 1;

  for (int i = tid; i < 64 * 65; i += 256) Sf[i] = 0.f;
  __syncthreads();

  for (int c = 0; c < TT / 64; ++c) {
    const int c0   = c * 64;
    const size_t u = (size_t)(c * NBH + bh);
    const ushort* base = (const ushort*)(SA + u * 24576);
    const float egC = egCg[u];

    // b1: load 5 matrices to LDS; cast Sf -> Y2-left [bar]
    {
#pragma unroll
      for (int r = 0; r < 2; ++r) {
        const int idx = tid + r * 256;       // 0..511
        const int row = idx >> 3, c8 = idx & 7;
        *(uint4*)((ushort*)Wl + row * 72 + c8 * 8) =
            *(const uint4*)(base + idx * 8);                       // W
        *(uint4*)((ushort*)X2 + row * 144 + 72 + c8 * 8) =
            *(const uint4*)(base + 4096 + idx * 8);                // P
        *(uint4*)((ushort*)X2 + row * 144 + c8 * 8) =
            *(const uint4*)(base + 8192 + idx * 8);                // Qg
        *(uint4*)((ushort*)KsTl + row * 72 + c8 * 8) =
            *(const uint4*)(base + 12288 + idx * 8);               // KsT
        *(uint4*)((ushort*)Zl + row * 72 + c8 * 8) =
            *(const uint4*)(base + 16384 + row * 128 + H * 64 + c8 * 8);  // Z half
      }
      const int v = tid >> 2, ds = tid & 3;
#pragma unroll
      for (int e = 0; e < 16; ++e)
        Y2[v * 144 + ds * 16 + e] = (_Float16)Sf[v * 65 + ds * 16 + e];
    }
    __syncthreads();

    // b2: U = Z - W @ S0 -> Y2-right [bar]
    {
      f32x4 accU[2][2];
      gemm64(Wl, 72, Y2, 144, wr, wc, lane, 2, 0, accU);
#pragma unroll
      for (int m = 0; m < 2; ++m)
#pragma unroll
        for (int n = 0; n < 2; ++n)
#pragma unroll
          for (int j = 0; j < 4; ++j) {
            const int row = wr * 32 + m * 16 + (lane >> 4) * 4 + j;  // t
            const int col = wc * 32 + n * 16 + (lane & 15);          // v
            const float uval = (float)Zl[row * 72 + col] - accU[m][n][j];
            Y2[col * 144 + 72 + row] = (_Float16)uval;
          }
    }
    __syncthreads();

    // b3: S = egC*S + KsT@U ; O = [Qg|P]@[S0^T|U^T]^T -> o [bar]
    {
      f32x4 accS[2][2], accO[2][2];
      gemm64(KsTl, 72, Y2 + 72, 144, wr, wc, lane, 2, 0, accS);
      gemm64(X2, 144, Y2, 144, wr, wc, lane, 4, 8, accO);
#pragma unroll
      for (int m = 0; m < 2; ++m)
#pragma unroll
        for (int n = 0; n < 2; ++n)
#pragma unroll
          for (int j = 0; j < 4; ++j) {
            const int row = wr * 32 + m * 16 + (lane >> 4) * 4 + j;  // d (S) / t (O)
            const int col = wc * 32 + n * 16 + (lane & 15);          // v
            Sf[col * 65 + row] = egC * Sf[col * 65 + row] + accS[m][n][j];
            o[(((size_t)b * TT + c0 + row) * HH + h) * 128 + H * 64 + col] = accO[m][n][j];
          }
    }
    __syncthreads();
  }
}

// ---------------------------------------------------------------------------
// RMS norm over 128 + SiLU gate; emits fp16 for the final GEMM.
// ---------------------------------------------------------------------------
__global__ void rmsgate_kernel(const float* __restrict__ o, const float* __restrict__ gpre,
                               ushort* __restrict__ gof)
{
  int gid  = blockIdx.x * blockDim.x + threadIdx.x;
  int wid  = gid >> 6;
  int lane = threadIdx.x & 63;
  if (wid >= BB * TT * HH) return;
  int h = wid % HH;
  int m = wid / HH;
  const float* orow = o + (size_t)wid * 128;
  float2 ov = *(const float2*)(orow + lane * 2);
  float ss = ov.x * ov.x + ov.y * ov.y;
#pragma unroll
  for (int mm = 32; mm >= 1; mm >>= 1) ss += __shfl_xor(ss, mm, 64);
  float scale = rsqrtf(ss * (1.f / 128.f) + EPSF);
  const float* gr = gpre + (size_t)m * TVv + h * 128 + lane * 2;
  float o0 = ov.x * scale * siluf(gr[0]);
  float o1 = ov.y * scale * siluf(gr[1]);
  *(uint*)(gof + (size_t)m * TVv + h * 128 + lane * 2) = pk2h(o0, o1);
}

// ---------------------------------------------------------------------------
extern "C" void kernel_launch(void* const* d_in, const int* in_sizes, int n_in,
                              void* d_out, int out_size, void* d_ws, size_t ws_size,
                              hipStream_t stream) {
  (void)in_sizes; (void)n_in; (void)out_size; (void)ws_size;
  const float* x       = (const float*)d_in[0];
  const float* w_q     = (const float*)d_in[1];
  const float* w_k     = (const float*)d_in[2];
  const float* w_v     = (const float*)d_in[3];
  const float* w_a     = (const float*)d_in[4];
  const float* w_b     = (const float*)d_in[5];
  const float* w_g     = (const float*)d_in[6];
  const float* w_out   = (const float*)d_in[7];
  const float* A_log   = (const float*)d_in[8];
  const float* dt_bias = (const float*)d_in[9];
  const float* qcw     = (const float*)d_in[10];
  const float* kcw     = (const float*)d_in[11];
  const float* vcw     = (const float*)d_in[12];

  // Workspace (63.11 MB proven footprint), time-multiplexed:
  //  ws[0..6291456)        : qkv_pre -> SA scratch + egCg -> gof
  //  ws[6291456..9437184)  : g_pre
  //  ws[9437184..15728640) : Cu: xf+wcat -> qc/kc/vc -> o + woutf
  //  ws[15728640..15777792): abi
  float* ws      = (float*)d_ws;
  float* qkv_pre = ws;
  float* g_pre   = ws + 6291456;
  float* Cu      = ws + 9437184;
  float* abi     = ws + 15728640;

  ushort* xf    = (ushort*)Cu;
  ushort* wcat  = (ushort*)(Cu + 1572864);

  float* qc = Cu;
  float* kc = Cu + 1572864;
  float* vc = Cu + 3145728;

  _Float16* SA   = (_Float16*)ws;              // 384 units * 24576 f16
  float*    egCg = ws + 4718592;               // 384 floats

  float*  o     = Cu;                          // overwrites dead qc/kc
  ushort* woutf = (ushort*)(Cu + 3145728);     // overwrites dead vc
  ushort* gof   = (ushort*)ws;                 // overwrites dead SA scratch

  const int M = BB * TT;  // 2048
  dim3 blk(256);

  // 1) fp16 casts
  cast_f16_kernel<<<1536, blk, 0, stream>>>(x, xf);
  cast_w4_kernel<<<3456, blk, 0, stream>>>(w_q, w_k, w_v, w_g, wcat);

  // 2) fused qkv+g projection (2-phase pipelined)
  gemm_f16<<<dim3(NQKVG / 128, M / 128), blk, 0, stream>>>(
      xf, wcat, qkv_pre, g_pre, M, NQKVG, DD, CQKV, TVv, CQKV);

  // 3) gating coefficients
  gate_kernel<<<M, blk, 0, stream>>>(x, w_a, w_b, A_log, dt_bias, abi);

  // 4) conv + SiLU + L2 norm
  conv_silu_kernel<<<24576, blk, 0, stream>>>(qkv_pre, qcw, kcw, vcw, qc, kc, vc);

  // 5) scan: chunk-parallel phase A, serial phase B (R18 form)
  scan_phaseA<<<16 * NBH, blk, 0, stream>>>(qc, kc, vc, abi, SA, egCg);
  scan_phaseB<<<2 * NBH, blk, 0, stream>>>(SA, egCg, o);

  // 6) cast w_out (into dead vc region)
  cast_f16_kernel<<<1152, blk, 0, stream>>>(w_out, woutf);

  // 7) RMS norm + SiLU gate (gof overwrites dead SA scratch)
  rmsgate_kernel<<<6144, blk, 0, stream>>>(o, g_pre, gof);

  // 8) output projection (2-phase pipelined)
  gemm_f16<<<dim3(TVv / 128, M / 128), blk, 0, stream>>>(
      gof, woutf, (float*)d_out, (float*)d_out, M, TVv, DD, TVv, TVv, TVv);
}

// Round 21
// 230.010 us; speedup vs baseline: 1.1141x; 1.0075x over previous
//
#include <hip/hip_runtime.h>
#include <math.h>

#define BB 2
#define TT 1024
#define DD 1536
#define HH 12
#define TQK 768
#define TVv 1536
#define CQKV 3072
#define NQKVG 4608
#define EPSF 1e-6f
#define NBH (BB * HH)   // 24

typedef __attribute__((ext_vector_type(8))) _Float16 half8v;
typedef __attribute__((ext_vector_type(4))) float f32x4;

__device__ __forceinline__ float siluf(float x) { return x / (1.f + expf(-x)); }

__device__ __forceinline__ uint pk2h(float a, float b) {
  union { _Float16 h[2]; uint u; } p;
  p.h[0] = (_Float16)a; p.h[1] = (_Float16)b;
  return p.u;
}

// async global->LDS (GEMM staging)
__device__ __forceinline__ void gload16(const void* g, void* l) {
  __builtin_amdgcn_global_load_lds(
      (const __attribute__((address_space(1))) void*)g,
      (__attribute__((address_space(3))) void*)l, 16, 0, 0);
}

// ---------------------------------------------------------------------------
// fp16 MFMA GEMM, 2-phase + COUNTED vmcnt (T4): stage tile k+1, then wait
// vmcnt(8) -- only tile k's loads (older) must land; k+1's 8 stay in flight
// across a RAW s_barrier (no vmcnt(0) drain in the loop). Second raw barrier
// after compute guards the buffer overwrite (ds_reads all consumed by MFMA).
// ---------------------------------------------------------------------------
__global__ __launch_bounds__(256) void gemm_f16(
    const ushort* __restrict__ X, const ushort* __restrict__ W,
    float* __restrict__ C1, float* __restrict__ C2,
    int M, int N, int K, int ldc1, int ldc2, int nsplit)
{
  __shared__ ushort Ah[2][128 * 64];
  __shared__ ushort Bh[2][128 * 64];
  const int tid  = threadIdx.x;
  const int lane = tid & 63;
  const int w    = tid >> 6;
  const int wr   = w >> 1, wc = w & 1;
  const int r0   = blockIdx.y * 128, c0 = blockIdx.x * 128;

  const int dr   = lane >> 3;
  const int slot = (lane & 7) ^ dr;

  f32x4 acc[4][4];
#pragma unroll
  for (int m = 0; m < 4; ++m)
#pragma unroll
    for (int n = 0; n < 4; ++n)
#pragma unroll
      for (int j = 0; j < 4; ++j) acc[m][n][j] = 0.f;

#define GSTAGE(B, K0) do { \
    _Pragma("unroll") \
    for (int j = 0; j < 4; ++j) { \
      const int row  = (w * 4 + j) * 8 + dr; \
      const size_t xo = (size_t)(r0 + row) * K + (K0) + slot * 8; \
      const size_t wo = (size_t)(c0 + row) * K + (K0) + slot * 8; \
      const int ldso = (w * 4 + j) * 512; \
      gload16(X + xo, &Ah[B][ldso]); \
      gload16(W + wo, &Bh[B][ldso]); \
    } \
  } while (0)

#define GCOMP(B) do { \
    _Pragma("unroll") \
    for (int kk = 0; kk < 2; ++kk) { \
      const int kc8 = kk * 4 + (lane >> 4); \
      const int sw  = (kc8 ^ (lane & 7)) << 3; \
      half8v a[4], b[4]; \
      _Pragma("unroll") \
      for (int m = 0; m < 4; ++m) \
        a[m] = *(const half8v*)(&Ah[B][(wr * 64 + m * 16 + (lane & 15)) * 64 + sw]); \
      _Pragma("unroll") \
      for (int n = 0; n < 4; ++n) \
        b[n] = *(const half8v*)(&Bh[B][(wc * 64 + n * 16 + (lane & 15)) * 64 + sw]); \
      _Pragma("unroll") \
      for (int m = 0; m < 4; ++m) \
        _Pragma("unroll") \
        for (int n = 0; n < 4; ++n) \
          acc[m][n] = __builtin_amdgcn_mfma_f32_16x16x32_f16(a[m], b[n], acc[m][n], 0, 0, 0); \
    } \
  } while (0)

  GSTAGE(0, 0);                       // 8 loads in flight
  int cur = 0;
  const int nks = K / 64;
  for (int ks = 0; ks < nks; ++ks) {
    if (ks + 1 < nks) {
      GSTAGE(cur ^ 1, (ks + 1) * 64);                      // +8 newer
      asm volatile("s_waitcnt vmcnt(8)" ::: "memory");     // tile-k landed
    } else {
      asm volatile("s_waitcnt vmcnt(0)" ::: "memory");     // tail
    }
    __builtin_amdgcn_s_barrier();                          // raw: no drain
    __builtin_amdgcn_sched_barrier(0);
    GCOMP(cur);
    __builtin_amdgcn_s_barrier();                          // guard overwrite
    __builtin_amdgcn_sched_barrier(0);
    cur ^= 1;
  }
#undef GSTAGE
#undef GCOMP

  float* Cp; int ldc, cc0;
  if (c0 < nsplit) { Cp = C1; ldc = ldc1; cc0 = c0; }
  else             { Cp = C2; ldc = ldc2; cc0 = c0 - nsplit; }

  const int crow = (lane >> 4) * 4;
  const int ccol = lane & 15;
#pragma unroll
  for (int m = 0; m < 4; ++m)
#pragma unroll
    for (int j = 0; j < 4; ++j) {
      float* cp = Cp + (size_t)(r0 + wr * 64 + m * 16 + crow + j) * ldc + cc0 + wc * 64 + ccol;
#pragma unroll
      for (int n = 0; n < 4; ++n) cp[n * 16] = acc[m][n][j];
    }
}

// ---------------------------------------------------------------------------
// f32 -> fp16 casts.
// ---------------------------------------------------------------------------
__device__ __forceinline__ void cast8_store(const float* f, ushort* dst, size_t e)
{
  uint4 pk;
  pk.x = pk2h(f[0], f[1]); pk.y = pk2h(f[2], f[3]);
  pk.z = pk2h(f[4], f[5]); pk.w = pk2h(f[6], f[7]);
  *(uint4*)(dst + e) = pk;
}

__global__ void cast_f16_kernel(const float* __restrict__ src, ushort* __restrict__ dst)
{
  int cid = blockIdx.x * blockDim.x + threadIdx.x;
  size_t e = (size_t)cid * 8;
  float f[8];
  *(float4*)(f)     = *(const float4*)(src + e);
  *(float4*)(f + 4) = *(const float4*)(src + e + 4);
  cast8_store(f, dst, e);
}

__global__ void cast_w4_kernel(const float* __restrict__ wq, const float* __restrict__ wk,
                               const float* __restrict__ wv, const float* __restrict__ wg,
                               ushort* __restrict__ dst)
{
  int cid = blockIdx.x * blockDim.x + threadIdx.x;
  size_t e = (size_t)cid * 8;
  const float* src; size_t off;
  if (e < 1179648)      { src = wq; off = e; }
  else if (e < 2359296) { src = wk; off = e - 1179648; }
  else if (e < 4718592) { src = wv; off = e - 2359296; }
  else                  { src = wg; off = e - 4718592; }
  float f[8];
  *(float4*)(f)     = *(const float4*)(src + off);
  *(float4*)(f + 4) = *(const float4*)(src + off + 4);
  cast8_store(f, dst, e);
}

// ---------------------------------------------------------------------------
// Causal depthwise conv (K=4) + SiLU + fused L2-norm (q,k heads).
// ---------------------------------------------------------------------------
__global__ void conv_silu_kernel(
    const float* __restrict__ pre,
    const float* __restrict__ qw, const float* __restrict__ kw, const float* __restrict__ vw,
    float* __restrict__ qc, float* __restrict__ kc, float* __restrict__ vc)
{
  int idx = blockIdx.x * blockDim.x + threadIdx.x;
  int c  = idx % CQKV;
  int bt = idx / CQKV;
  int t  = bt % TT;
  int b  = bt / TT;

  const float* wp;
  if (c < TQK)          wp = qw + (size_t)c * 4;
  else if (c < 2 * TQK) wp = kw + (size_t)(c - TQK) * 4;
  else                  wp = vw + (size_t)(c - 2 * TQK) * 4;

  float s = 0.f;
#pragma unroll
  for (int j = 0; j < 4; ++j) {
    int ts = t - 3 + j;
    if (ts >= 0) s = fmaf(pre[(size_t)(b * TT + ts) * CQKV + c], wp[j], s);
  }
  s = siluf(s);

  if (c < 2 * TQK) {
    float ss = s * s;
#pragma unroll
    for (int m = 32; m >= 1; m >>= 1) ss += __shfl_xor(ss, m, 64);
    s = s / fmaxf(sqrtf(ss), EPSF);
  }

  if (c < TQK) {
    int h = c >> 6, d = c & 63;
    qc[((size_t)(b * HH + h) * TT + t) * 64 + d] = s;
  } else if (c < 2 * TQK) {
    int c2 = c - TQK; int h = c2 >> 6, d = c2 & 63;
    kc[((size_t)(b * HH + h) * TT + t) * 64 + d] = s;
  } else {
    int c2 = c - 2 * TQK; int h = c2 >> 7, d = c2 & 127;
    vc[((size_t)(b * HH + h) * TT + t) * 128 + d] = s;
  }
}

// ---------------------------------------------------------------------------
// Gating: block per row; writes interleaved (alpha,beta).
// ---------------------------------------------------------------------------
__global__ __launch_bounds__(256) void gate_kernel(
    const float* __restrict__ x, const float* __restrict__ w_a, const float* __restrict__ w_b,
    const float* __restrict__ A_log, const float* __restrict__ dt_bias,
    float* __restrict__ abi)
{
  const int m    = blockIdx.x;
  const int w    = threadIdx.x >> 6;
  const int lane = threadIdx.x & 63;
  const float* xr = x + (size_t)m * DD;
  float xv[24];
#pragma unroll
  for (int i = 0; i < 24; ++i) xv[i] = xr[lane + i * 64];
  const int b = m / TT, t = m % TT;
#pragma unroll
  for (int j = 0; j < 6; ++j) {
    int o = w * 6 + j;
    bool isA = o < HH;
    int h = isA ? o : o - HH;
    const float* wr = (isA ? w_a : w_b) + (size_t)h * DD;
    float s = 0.f;
#pragma unroll
    for (int i = 0; i < 24; ++i) s = fmaf(xv[i], wr[lane + i * 64], s);
#pragma unroll
    for (int mm = 32; mm >= 1; mm >>= 1) s += __shfl_xor(s, mm, 64);
    if (lane == 0) {
      size_t idx = ((size_t)(b * HH + h) * TT + t) * 2;
      if (isA) {
        float a  = s + dt_bias[h];
        float sp = (a > 20.f) ? a : log1pf(expf(a));
        abi[idx] = expf(-expf(A_log[h]) * sp);
      } else {
        abi[idx + 1] = 2.f / (1.f + expf(-s));
      }
    }
  }
}

// ---------------------------------------------------------------------------
// Shared 64x64 MFMA GEMM helper (verified): C = X @ Y^T.
// ---------------------------------------------------------------------------
__device__ __forceinline__ void gemm64(
    const _Float16* XB, int xstr, const _Float16* YB, int ystr,
    int wr, int wc, int lane, int ksteps, int kpad, f32x4 acc[2][2])
{
#pragma unroll
  for (int m = 0; m < 2; ++m)
#pragma unroll
    for (int n = 0; n < 2; ++n)
#pragma unroll
      for (int j = 0; j < 4; ++j) acc[m][n][j] = 0.f;
#pragma unroll 4
  for (int kk = 0; kk < ksteps; ++kk) {
    const int koff = kk * 32 + ((kk >> 1) ? kpad : 0) + (lane >> 4) * 8;
    half8v a[2], b[2];
#pragma unroll
    for (int m = 0; m < 2; ++m)
      a[m] = *(const half8v*)(XB + (wr * 32 + m * 16 + (lane & 15)) * xstr + koff);
#pragma unroll
    for (int n = 0; n < 2; ++n)
      b[n] = *(const half8v*)(YB + (wc * 32 + n * 16 + (lane & 15)) * ystr + koff);
#pragma unroll
    for (int m = 0; m < 2; ++m)
#pragma unroll
      for (int n = 0; n < 2; ++n)
        acc[m][n] = __builtin_amdgcn_mfma_f32_16x16x32_f16(a[m], b[n], acc[m][n], 0, 0, 0);
  }
}

// ---------------------------------------------------------------------------
// Scan phase A (chunk-parallel, 384 blocks): per chunk compute and store f16:
//   W = T diag(beta e^g) K   (4096)     P  = mask(e^dg Q K^T)  (4096)
//   Qg = e^g q               (4096)     KsT[d][t] = e^{gC-g_t} k (4096)
//   Z = T V                  (8192)     egCg[unit] = e^{gC}
// ---------------------------------------------------------------------------
__global__ __launch_bounds__(256) void scan_phaseA(
    const float* __restrict__ qc, const float* __restrict__ kc, const float* __restrict__ vc,
    const float* __restrict__ abi, _Float16* __restrict__ SA, float* __restrict__ egCg)
{
  __shared__ _Float16 Kf[64 * 72];      // aliased as Tf after ph2
  __shared__ _Float16 Qf[64 * 72];
  __shared__ _Float16 KbT[64 * 72];     // [d][i] = betg_i k_i[d]
  __shared__ _Float16 VT[128 * 72];     // [v][t]
  __shared__ float    Af[64 * 67];
  __shared__ float    Tg[64 * 67];
  __shared__ float    tmpf[1088];
  __shared__ float    g_s[64], bet_s[64], betg_s[64], eg_s[64], eKs_s[64];
  _Float16* Tf = Kf;

  const int unit = blockIdx.x;
  const int bh   = unit % NBH;
  const int c    = unit / NBH;
  const int c0   = c * 64;
  const int tid  = threadIdx.x;
  const int lane = tid & 63;
  const int w    = tid >> 6;
  const int wr   = w >> 1, wc = w & 1;

  _Float16* SAu = SA + (size_t)unit * 24576;

  // ph0: scalars [bar]
  if (tid < 64) {
    float2 ab = *(const float2*)(abi + ((size_t)bh * TT + c0 + tid) * 2);
    float gg = logf(ab.x);
#pragma unroll
    for (int off = 1; off < 64; off <<= 1) {
      float up = __shfl_up(gg, off, 64);
      if (tid >= off) gg += up;
    }
    float gC = __shfl(gg, 63, 64);
    g_s[tid]    = gg;
    bet_s[tid]  = ab.y;
    betg_s[tid] = ab.y * expf(gg);
    eg_s[tid]   = expf(gg);
    eKs_s[tid]  = expf(gC - gg);
    if (tid == 0) egCg[unit] = expf(gC);
  }
  __syncthreads();

  // ph1: build Kf, KbT, Qf, VT; store Qg, KsT scratch; zero Tg [bar]
  {
    const int t  = tid >> 2;
    const int dg = tid & 3;
    const float* krow = kc + ((size_t)bh * TT + c0 + t) * 64 + dg * 16;
    const float* qrow = qc + ((size_t)bh * TT + c0 + t) * 64 + dg * 16;
    const float bg = betg_s[t], egt = eg_s[t], ekt = eKs_s[t];
#pragma unroll
    for (int q4 = 0; q4 < 4; ++q4) {
      float4 kv = *(const float4*)(krow + q4 * 4);
      float4 qv = *(const float4*)(qrow + q4 * 4);
      const int d = dg * 16 + q4 * 4;
      const float kf[4] = {kv.x, kv.y, kv.z, kv.w};
      const float qf[4] = {qv.x, qv.y, qv.z, qv.w};
#pragma unroll
      for (int e = 0; e < 4; ++e) {
        Kf[t * 72 + d + e]        = (_Float16)kf[e];
        KbT[(d + e) * 72 + t]     = (_Float16)(kf[e] * bg);
        Qf[t * 72 + d + e]        = (_Float16)qf[e];
        SAu[8192 + t * 64 + d + e]  = (_Float16)(qf[e] * egt);   // Qg
        SAu[12288 + (d + e) * 64 + t] = (_Float16)(kf[e] * ekt); // KsT [d][t]
      }
    }
    const float* vrow = vc + ((size_t)bh * TT + c0 + t) * 128 + dg * 32;
#pragma unroll
    for (int q4 = 0; q4 < 8; ++q4) {
      float4 vv = *(const float4*)(vrow + q4 * 4);
      const int v = dg * 32 + q4 * 4;
      VT[(v + 0) * 72 + t] = (_Float16)vv.x;
      VT[(v + 1) * 72 + t] = (_Float16)vv.y;
      VT[(v + 2) * 72 + t] = (_Float16)vv.z;
      VT[(v + 3) * 72 + t] = (_Float16)vv.w;
    }
    for (int i = tid; i < 64 * 67; i += 256) Tg[i] = 0.f;
  }
  __syncthreads();

  // ph2: A = mask(beta e^dg K K^T) -> Af ; P = mask(e^dg Q K^T) -> scratch [bar]
  {
    f32x4 accA[2][2], accP[2][2];
    gemm64(Kf, 72, Kf, 72, wr, wc, lane, 2, 0, accA);
    gemm64(Qf, 72, Kf, 72, wr, wc, lane, 2, 0, accP);
#pragma unroll
    for (int m = 0; m < 2; ++m)
#pragma unroll
      for (int n = 0; n < 2; ++n)
#pragma unroll
        for (int j = 0; j < 4; ++j) {
          const int row = wr * 32 + m * 16 + (lane >> 4) * 4 + j;
          const int col = wc * 32 + n * 16 + (lane & 15);
          const float eg = expf(g_s[row] - g_s[col]);
          Af[row * 67 + col] = (col < row) ? bet_s[row] * eg * accA[m][n][j] : 0.f;
          SAu[4096 + row * 64 + col] =
              (col <= row) ? (_Float16)(eg * accP[m][n][j]) : (_Float16)0.f;
        }
  }
  __syncthreads();

  // ph3a: 4 diagonal 16x16 inverses into Tg [bar]
  if (lane < 16) {
    const int R = w * 16;
    Tg[R * 67 + R + lane] = (lane == 0) ? 1.f : 0.f;
    for (int t = 1; t < 16; ++t) {
      float s = 0.f;
      for (int i = 0; i < t; ++i)
        s = fmaf(Af[(R + t) * 67 + R + i], Tg[(R + i) * 67 + R + lane], s);
      Tg[(R + t) * 67 + R + lane] = ((lane == t) ? 1.f : 0.f) - s;
    }
  }
  __syncthreads();
  // ph3b-1 [bar]
  {
    const int r = (tid >> 4) & 15, cx = tid & 15;
#pragma unroll
    for (int p = 0; p < 2; ++p) {
      float s = 0.f;
      for (int i = 0; i < 16; ++i)
        s = fmaf(Af[(p * 32 + 16 + r) * 67 + p * 32 + i],
                 Tg[(p * 32 + i) * 67 + p * 32 + cx], s);
      tmpf[p * 272 + r * 17 + cx] = s;
    }
  }
  __syncthreads();
  // ph3b-2 [bar]
  {
    const int r = (tid >> 4) & 15, cx = tid & 15;
#pragma unroll
    for (int p = 0; p < 2; ++p) {
      float s = 0.f;
      for (int i = 0; i < 16; ++i)
        s = fmaf(Tg[(p * 32 + 16 + r) * 67 + p * 32 + 16 + i],
                 tmpf[p * 272 + i * 17 + cx], s);
      Tg[(p * 32 + 16 + r) * 67 + p * 32 + cx] = -s;
    }
  }
  __syncthreads();
  // ph3c-1 [bar]
  {
#pragma unroll
    for (int rep = 0; rep < 4; ++rep) {
      const int idx = tid + rep * 256;
      const int r = idx >> 5, cx = idx & 31;
      float s = 0.f;
      for (int i = 0; i < 32; ++i)
        s = fmaf(Af[(32 + r) * 67 + i], Tg[i * 67 + cx], s);
      tmpf[r * 33 + cx] = s;
    }
  }
  __syncthreads();
  // ph3c-2 [bar]
  {
#pragma unroll
    for (int rep = 0; rep < 4; ++rep) {
      const int idx = tid + rep * 256;
      const int r = idx >> 5, cx = idx & 31;
      float s = 0.f;
      for (int i = 0; i < 32; ++i)
        s = fmaf(Tg[(32 + r) * 67 + 32 + i], tmpf[i * 33 + cx], s);
      Tg[(32 + r) * 67 + cx] = -s;
    }
  }
  __syncthreads();

  // ph4: cast Tg -> Tf (aliases Kf; Kf dead after ph2) [bar]
  {
    const int t = tid >> 2, qg = tid & 3;
#pragma unroll
    for (int e = 0; e < 16; ++e) {
      const int i = qg * 16 + e;
      Tf[t * 72 + i] = (_Float16)Tg[t * 67 + i];
    }
  }
  __syncthreads();

  // ph5: W = T @ KbT^T -> scratch ; Z = T @ VT^T (two halves) -> scratch
  {
    f32x4 accW[2][2];
    gemm64(Tf, 72, KbT, 72, wr, wc, lane, 2, 0, accW);
#pragma unroll
    for (int m = 0; m < 2; ++m)
#pragma unroll
      for (int n = 0; n < 2; ++n)
#pragma unroll
        for (int j = 0; j < 4; ++j) {
          const int row = wr * 32 + m * 16 + (lane >> 4) * 4 + j;
          const int col = wc * 32 + n * 16 + (lane & 15);
          SAu[row * 64 + col] = (_Float16)accW[m][n][j];
        }
#pragma unroll
    for (int H = 0; H < 2; ++H) {
      f32x4 accZ[2][2];
      gemm64(Tf, 72, VT + H * 64 * 72, 72, wr, wc, lane, 2, 0, accZ);
#pragma unroll
      for (int m = 0; m < 2; ++m)
#pragma unroll
        for (int n = 0; n < 2; ++n)
#pragma unroll
          for (int j = 0; j < 4; ++j) {
            const int row = wr * 32 + m * 16 + (lane >> 4) * 4 + j;
            const int col = wc * 32 + n * 16 + (lane & 15);
            SAu[16384 + row * 128 + H * 64 + col] = (_Float16)accZ[m][n][j];
          }
    }
  }
}

// ---------------------------------------------------------------------------
// Scan phase B (serial over 16 chunks; 48 blocks = bh x 2 v-halves): pure
// scratch consumer (R18-proven form).
// ---------------------------------------------------------------------------
__global__ __launch_bounds__(256) void scan_phaseB(
    const _Float16* __restrict__ SA, const float* __restrict__ egCg,
    float* __restrict__ o)
{
  __shared__ float    Sf[64 * 65];      // S^T half [v][d] f32 (persistent)
  __shared__ _Float16 Wl[64 * 72];      // [t][d]
  __shared__ _Float16 KsTl[64 * 72];    // [d][t]
  __shared__ _Float16 Zl[64 * 72];      // [t][v-half]
  __shared__ _Float16 X2[64 * 144];     // [t][0:64]=Qg, [72:136]=P
  __shared__ _Float16 Y2[64 * 144];     // [v][0:64]=S0^T f16, [72:136]=U^T

  const int blk  = blockIdx.x;
  const int bh   = blk % NBH;
  const int H    = blk / NBH;           // 0..1 (v half)
  const int b    = bh / HH, h = bh % HH;
  const int tid  = threadIdx.x;
  const int lane = tid & 63;
  const int w    = tid >> 6;
  const int wr   = w >> 1, wc = w & 1;

  for (int i = tid; i < 64 * 65; i += 256) Sf[i] = 0.f;
  __syncthreads();

  for (int c = 0; c < TT / 64; ++c) {
    const int c0   = c * 64;
    const size_t u = (size_t)(c * NBH + bh);
    const ushort* base = (const ushort*)(SA + u * 24576);
    const float egC = egCg[u];

    // b1: load 5 matrices to LDS; cast Sf -> Y2-left [bar]
    {
#pragma unroll
      for (int r = 0; r < 2; ++r) {
        const int idx = tid + r * 256;       // 0..511
        const int row = idx >> 3, c8 = idx & 7;
        *(uint4*)((ushort*)Wl + row * 72 + c8 * 8) =
            *(const uint4*)(base + idx * 8);                       // W
        *(uint4*)((ushort*)X2 + row * 144 + 72 + c8 * 8) =
            *(const uint4*)(base + 4096 + idx * 8);                // P
        *(uint4*)((ushort*)X2 + row * 144 + c8 * 8) =
            *(const uint4*)(base + 8192 + idx * 8);                // Qg
        *(uint4*)((ushort*)KsTl + row * 72 + c8 * 8) =
            *(const uint4*)(base + 12288 + idx * 8);               // KsT
        *(uint4*)((ushort*)Zl + row * 72 + c8 * 8) =
            *(const uint4*)(base + 16384 + row * 128 + H * 64 + c8 * 8);  // Z half
      }
      const int v = tid >> 2, ds = tid & 3;
#pragma unroll
      for (int e = 0; e < 16; ++e)
        Y2[v * 144 + ds * 16 + e] = (_Float16)Sf[v * 65 + ds * 16 + e];
    }
    __syncthreads();

    // b2: U = Z - W @ S0 -> Y2-right [bar]
    {
      f32x4 accU[2][2];
      gemm64(Wl, 72, Y2, 144, wr, wc, lane, 2, 0, accU);
#pragma unroll
      for (int m = 0; m < 2; ++m)
#pragma unroll
        for (int n = 0; n < 2; ++n)
#pragma unroll
          for (int j = 0; j < 4; ++j) {
            const int row = wr * 32 + m * 16 + (lane >> 4) * 4 + j;  // t
            const int col = wc * 32 + n * 16 + (lane & 15);          // v
            const float uval = (float)Zl[row * 72 + col] - accU[m][n][j];
            Y2[col * 144 + 72 + row] = (_Float16)uval;
          }
    }
    __syncthreads();

    // b3: S = egC*S + KsT@U ; O = [Qg|P]@[S0^T|U^T]^T -> o [bar]
    {
      f32x4 accS[2][2], accO[2][2];
      gemm64(KsTl, 72, Y2 + 72, 144, wr, wc, lane, 2, 0, accS);
      gemm64(X2, 144, Y2, 144, wr, wc, lane, 4, 8, accO);
#pragma unroll
      for (int m = 0; m < 2; ++m)
#pragma unroll
        for (int n = 0; n < 2; ++n)
#pragma unroll
          for (int j = 0; j < 4; ++j) {
            const int row = wr * 32 + m * 16 + (lane >> 4) * 4 + j;  // d (S) / t (O)
            const int col = wc * 32 + n * 16 + (lane & 15);          // v
            Sf[col * 65 + row] = egC * Sf[col * 65 + row] + accS[m][n][j];
            o[(((size_t)b * TT + c0 + row) * HH + h) * 128 + H * 64 + col] = accO[m][n][j];
          }
    }
    __syncthreads();
  }
}

// ---------------------------------------------------------------------------
// RMS norm over 128 + SiLU gate; emits fp16 for the final GEMM.
// ---------------------------------------------------------------------------
__global__ void rmsgate_kernel(const float* __restrict__ o, const float* __restrict__ gpre,
                               ushort* __restrict__ gof)
{
  int gid  = blockIdx.x * blockDim.x + threadIdx.x;
  int wid  = gid >> 6;
  int lane = threadIdx.x & 63;
  if (wid >= BB * TT * HH) return;
  int h = wid % HH;
  int m = wid / HH;
  const float* orow = o + (size_t)wid * 128;
  float2 ov = *(const float2*)(orow + lane * 2);
  float ss = ov.x * ov.x + ov.y * ov.y;
#pragma unroll
  for (int mm = 32; mm >= 1; mm >>= 1) ss += __shfl_xor(ss, mm, 64);
  float scale = rsqrtf(ss * (1.f / 128.f) + EPSF);
  const float* gr = gpre + (size_t)m * TVv + h * 128 + lane * 2;
  float o0 = ov.x * scale * siluf(gr[0]);
  float o1 = ov.y * scale * siluf(gr[1]);
  *(uint*)(gof + (size_t)m * TVv + h * 128 + lane * 2) = pk2h(o0, o1);
}

// ---------------------------------------------------------------------------
extern "C" void kernel_launch(void* const* d_in, const int* in_sizes, int n_in,
                              void* d_out, int out_size, void* d_ws, size_t ws_size,
                              hipStream_t stream) {
  (void)in_sizes; (void)n_in; (void)out_size; (void)ws_size;
  const float* x       = (const float*)d_in[0];
  const float* w_q     = (const float*)d_in[1];
  const float* w_k     = (const float*)d_in[2];
  const float* w_v     = (const float*)d_in[3];
  const float* w_a     = (const float*)d_in[4];
  const float* w_b     = (const float*)d_in[5];
  const float* w_g     = (const float*)d_in[6];
  const float* w_out   = (const float*)d_in[7];
  const float* A_log   = (const float*)d_in[8];
  const float* dt_bias = (const float*)d_in[9];
  const float* qcw     = (const float*)d_in[10];
  const float* kcw     = (const float*)d_in[11];
  const float* vcw     = (const float*)d_in[12];

  // Workspace (63.11 MB proven footprint), time-multiplexed:
  //  ws[0..6291456)        : qkv_pre -> SA scratch + egCg -> gof
  //  ws[6291456..9437184)  : g_pre
  //  ws[9437184..15728640) : Cu: xf+wcat -> qc/kc/vc -> o + woutf
  //  ws[15728640..15777792): abi
  float* ws      = (float*)d_ws;
  float* qkv_pre = ws;
  float* g_pre   = ws + 6291456;
  float* Cu      = ws + 9437184;
  float* abi     = ws + 15728640;

  ushort* xf    = (ushort*)Cu;
  ushort* wcat  = (ushort*)(Cu + 1572864);

  float* qc = Cu;
  float* kc = Cu + 1572864;
  float* vc = Cu + 3145728;

  _Float16* SA   = (_Float16*)ws;              // 384 units * 24576 f16
  float*    egCg = ws + 4718592;               // 384 floats

  float*  o     = Cu;                          // overwrites dead qc/kc
  ushort* woutf = (ushort*)(Cu + 3145728);     // overwrites dead vc
  ushort* gof   = (ushort*)ws;                 // overwrites dead SA scratch

  const int M = BB * TT;  // 2048
  dim3 blk(256);

  // 1) fp16 casts
  cast_f16_kernel<<<1536, blk, 0, stream>>>(x, xf);
  cast_w4_kernel<<<3456, blk, 0, stream>>>(w_q, w_k, w_v, w_g, wcat);

  // 2) fused qkv+g projection (counted-vmcnt pipeline)
  gemm_f16<<<dim3(NQKVG / 128, M / 128), blk, 0, stream>>>(
      xf, wcat, qkv_pre, g_pre, M, NQKVG, DD, CQKV, TVv, CQKV);

  // 3) gating coefficients
  gate_kernel<<<M, blk, 0, stream>>>(x, w_a, w_b, A_log, dt_bias, abi);

  // 4) conv + SiLU + L2 norm
  conv_silu_kernel<<<24576, blk, 0, stream>>>(qkv_pre, qcw, kcw, vcw, qc, kc, vc);

  // 5) scan: chunk-parallel phase A, serial phase B
  scan_phaseA<<<16 * NBH, blk, 0, stream>>>(qc, kc, vc, abi, SA, egCg);
  scan_phaseB<<<2 * NBH, blk, 0, stream>>>(SA, egCg, o);

  // 6) cast w_out (into dead vc region)
  cast_f16_kernel<<<1152, blk, 0, stream>>>(w_out, woutf);

  // 7) RMS norm + SiLU gate (gof overwrites dead SA scratch)
  rmsgate_kernel<<<6144, blk, 0, stream>>>(o, g_pre, gof);

  // 8) output projection (counted-vmcnt pipeline)
  gemm_f16<<<dim3(TVv / 128, M / 128), blk, 0, stream>>>(
      gof, woutf, (float*)d_out, (float*)d_out, M, TVv, DD, TVv, TVv, TVv);
}

// Round 22
// 220.078 us; speedup vs baseline: 1.1644x; 1.0451x over previous
//
#include <hip/hip_runtime.h>
#include <math.h>

#define BB 2
#define TT 1024
#define DD 1536
#define HH 12
#define TQK 768
#define TVv 1536
#define CQKV 3072
#define NQKVG 4608
#define EPSF 1e-6f
#define NBH (BB * HH)   // 24

typedef __attribute__((ext_vector_type(8))) _Float16 half8v;
typedef __attribute__((ext_vector_type(4))) float f32x4;

__device__ __forceinline__ float siluf(float x) { return x / (1.f + expf(-x)); }

__device__ __forceinline__ uint pk2h(float a, float b) {
  union { _Float16 h[2]; uint u; } p;
  p.h[0] = (_Float16)a; p.h[1] = (_Float16)b;
  return p.u;
}
__device__ __forceinline__ ushort f2h(float f) {
  _Float16 h = (_Float16)f; ushort u; __builtin_memcpy(&u, &h, 2); return u;
}
__device__ __forceinline__ float h2f(ushort u) {
  _Float16 h; __builtin_memcpy(&h, &u, 2); return (float)h;
}

// async global->LDS (GEMM staging)
__device__ __forceinline__ void gload16(const void* g, void* l) {
  __builtin_amdgcn_global_load_lds(
      (const __attribute__((address_space(1))) void*)g,
      (__attribute__((address_space(3))) void*)l, 16, 0, 0);
}

// ---------------------------------------------------------------------------
// fp16 MFMA GEMM, K-SPLIT: blockIdx.z selects K-range [z*KS, (z+1)*KS) and
// partial output buffer P + z*M*N (f16). Single-buffer 32KB LDS (R18/R20
// proven structure) for max co-residency: split-2 big = 1152 blocks
// (4.5/CU), split-4 final = 768 blocks (3/CU) -- the m97 TLP regime.
// ---------------------------------------------------------------------------
__global__ __launch_bounds__(256) void gemm_f16_ks(
    const ushort* __restrict__ X, const ushort* __restrict__ W,
    ushort* __restrict__ P, int M, int N, int K, int KS)
{
  __shared__ ushort Ah[128 * 64];
  __shared__ ushort Bh[128 * 64];
  const int tid  = threadIdx.x;
  const int lane = tid & 63;
  const int w    = tid >> 6;
  const int wr   = w >> 1, wc = w & 1;
  const int r0   = blockIdx.y * 128, c0 = blockIdx.x * 128;
  const int k0b  = blockIdx.z * KS;
  ushort* Pz = P + (size_t)blockIdx.z * M * N;

  const int dr   = lane >> 3;
  const int slot = (lane & 7) ^ dr;

  f32x4 acc[4][4];
#pragma unroll
  for (int m = 0; m < 4; ++m)
#pragma unroll
    for (int n = 0; n < 4; ++n)
#pragma unroll
      for (int j = 0; j < 4; ++j) acc[m][n][j] = 0.f;

  for (int k0 = k0b; k0 < k0b + KS; k0 += 64) {
#pragma unroll
    for (int j = 0; j < 4; ++j) {
      const int row  = (w * 4 + j) * 8 + dr;
      const size_t xo = (size_t)(r0 + row) * K + k0 + slot * 8;
      const size_t wo = (size_t)(c0 + row) * K + k0 + slot * 8;
      const int ldso = (w * 4 + j) * 512;
      gload16(X + xo, Ah + ldso);
      gload16(W + wo, Bh + ldso);
    }
    __syncthreads();
#pragma unroll
    for (int kk = 0; kk < 2; ++kk) {
      const int kc8 = kk * 4 + (lane >> 4);
      const int sw  = (kc8 ^ (lane & 7)) << 3;
      half8v a[4], b[4];
#pragma unroll
      for (int m = 0; m < 4; ++m)
        a[m] = *(const half8v*)(Ah + (wr * 64 + m * 16 + (lane & 15)) * 64 + sw);
#pragma unroll
      for (int n = 0; n < 4; ++n)
        b[n] = *(const half8v*)(Bh + (wc * 64 + n * 16 + (lane & 15)) * 64 + sw);
#pragma unroll
      for (int m = 0; m < 4; ++m)
#pragma unroll
        for (int n = 0; n < 4; ++n)
          acc[m][n] = __builtin_amdgcn_mfma_f32_16x16x32_f16(a[m], b[n], acc[m][n], 0, 0, 0);
    }
    __syncthreads();
  }

  const int crow = (lane >> 4) * 4;
  const int ccol = lane & 15;
#pragma unroll
  for (int m = 0; m < 4; ++m)
#pragma unroll
    for (int j = 0; j < 4; ++j) {
      ushort* cp = Pz + (size_t)(r0 + wr * 64 + m * 16 + crow + j) * N + c0 + wc * 64 + ccol;
#pragma unroll
      for (int n = 0; n < 4; ++n) cp[n * 16] = f2h(acc[m][n][j]);
    }
}

// ---------------------------------------------------------------------------
// f32 -> fp16 casts.
// ---------------------------------------------------------------------------
__device__ __forceinline__ void cast8_store(const float* f, ushort* dst, size_t e)
{
  uint4 pk;
  pk.x = pk2h(f[0], f[1]); pk.y = pk2h(f[2], f[3]);
  pk.z = pk2h(f[4], f[5]); pk.w = pk2h(f[6], f[7]);
  *(uint4*)(dst + e) = pk;
}

__global__ void cast_f16_kernel(const float* __restrict__ src, ushort* __restrict__ dst)
{
  int cid = blockIdx.x * blockDim.x + threadIdx.x;
  size_t e = (size_t)cid * 8;
  float f[8];
  *(float4*)(f)     = *(const float4*)(src + e);
  *(float4*)(f + 4) = *(const float4*)(src + e + 4);
  cast8_store(f, dst, e);
}

__global__ void cast_w4_kernel(const float* __restrict__ wq, const float* __restrict__ wk,
                               const float* __restrict__ wv, const float* __restrict__ wg,
                               ushort* __restrict__ dst)
{
  int cid = blockIdx.x * blockDim.x + threadIdx.x;
  size_t e = (size_t)cid * 8;
  const float* src; size_t off;
  if (e < 1179648)      { src = wq; off = e; }
  else if (e < 2359296) { src = wk; off = e - 1179648; }
  else if (e < 4718592) { src = wv; off = e - 2359296; }
  else                  { src = wg; off = e - 4718592; }
  float f[8];
  *(float4*)(f)     = *(const float4*)(src + off);
  *(float4*)(f + 4) = *(const float4*)(src + off + 4);
  cast8_store(f, dst, e);
}

// ---------------------------------------------------------------------------
// Causal depthwise conv (K=4) + SiLU + fused L2-norm. Reads the TWO f16
// K-split partials (pA+pB summed per tap); writes q/k/v as f16 (phaseA casts
// to f16 anyway). Row width of partials = 4608 (qkv cols [0..3072)).
// ---------------------------------------------------------------------------
__global__ void conv_silu_kernel(
    const ushort* __restrict__ pA, const ushort* __restrict__ pB,
    const float* __restrict__ qw, const float* __restrict__ kw, const float* __restrict__ vw,
    ushort* __restrict__ qc, ushort* __restrict__ kc, ushort* __restrict__ vc)
{
  int idx = blockIdx.x * blockDim.x + threadIdx.x;
  int c  = idx % CQKV;
  int bt = idx / CQKV;
  int t  = bt % TT;
  int b  = bt / TT;

  const float* wp;
  if (c < TQK)          wp = qw + (size_t)c * 4;
  else if (c < 2 * TQK) wp = kw + (size_t)(c - TQK) * 4;
  else                  wp = vw + (size_t)(c - 2 * TQK) * 4;

  float s = 0.f;
#pragma unroll
  for (int j = 0; j < 4; ++j) {
    int ts = t - 3 + j;
    if (ts >= 0) {
      size_t ii = (size_t)(b * TT + ts) * NQKVG + c;
      float v = h2f(pA[ii]) + h2f(pB[ii]);
      s = fmaf(v, wp[j], s);
    }
  }
  s = siluf(s);

  if (c < 2 * TQK) {           // q or k: fused L2 norm over the 64-lane head
    float ss = s * s;
#pragma unroll
    for (int m = 32; m >= 1; m >>= 1) ss += __shfl_xor(ss, m, 64);
    s = s / fmaxf(sqrtf(ss), EPSF);
  }

  if (c < TQK) {
    int h = c >> 6, d = c & 63;
    qc[((size_t)(b * HH + h) * TT + t) * 64 + d] = f2h(s);
  } else if (c < 2 * TQK) {
    int c2 = c - TQK; int h = c2 >> 6, d = c2 & 63;
    kc[((size_t)(b * HH + h) * TT + t) * 64 + d] = f2h(s);
  } else {
    int c2 = c - 2 * TQK; int h = c2 >> 7, d = c2 & 127;
    vc[((size_t)(b * HH + h) * TT + t) * 128 + d] = f2h(s);
  }
}

// ---------------------------------------------------------------------------
// gsum16: fold g-columns of the two big-GEMM partials into compact g16.
// ---------------------------------------------------------------------------
__global__ void gsum16_kernel(const ushort* __restrict__ pA, const ushort* __restrict__ pB,
                              ushort* __restrict__ g16)
{
  int cid = blockIdx.x * blockDim.x + threadIdx.x;
  int e   = cid * 8;                 // < 2048*1536
  int m   = e / TVv, j = e % TVv;
  size_t src = (size_t)m * NQKVG + CQKV + j;
  half8v a = *(const half8v*)(pA + src);
  half8v b = *(const half8v*)(pB + src);
  half8v r;
#pragma unroll
  for (int i = 0; i < 8; ++i) r[i] = (_Float16)((float)a[i] + (float)b[i]);
  *(half8v*)(g16 + e) = r;
}

// ---------------------------------------------------------------------------
// reduce4: d_out = sum of 4 f16 partials of the final GEMM.
// ---------------------------------------------------------------------------
__global__ void reduce4_kernel(const ushort* __restrict__ p, float* __restrict__ out)
{
  int cid = blockIdx.x * blockDim.x + threadIdx.x;
  size_t e = (size_t)cid * 8;
  float acc8[8];
#pragma unroll
  for (int i = 0; i < 8; ++i) acc8[i] = 0.f;
#pragma unroll
  for (int part = 0; part < 4; ++part) {
    half8v v = *(const half8v*)(p + (size_t)part * 3145728 + e);
#pragma unroll
    for (int i = 0; i < 8; ++i) acc8[i] += (float)v[i];
  }
  *(float4*)(out + e)     = make_float4(acc8[0], acc8[1], acc8[2], acc8[3]);
  *(float4*)(out + e + 4) = make_float4(acc8[4], acc8[5], acc8[6], acc8[7]);
}

// ---------------------------------------------------------------------------
// Gating: block per row; writes interleaved (alpha,beta).
// ---------------------------------------------------------------------------
__global__ __launch_bounds__(256) void gate_kernel(
    const float* __restrict__ x, const float* __restrict__ w_a, const float* __restrict__ w_b,
    const float* __restrict__ A_log, const float* __restrict__ dt_bias,
    float* __restrict__ abi)
{
  const int m    = blockIdx.x;
  const int w    = threadIdx.x >> 6;
  const int lane = threadIdx.x & 63;
  const float* xr = x + (size_t)m * DD;
  float xv[24];
#pragma unroll
  for (int i = 0; i < 24; ++i) xv[i] = xr[lane + i * 64];
  const int b = m / TT, t = m % TT;
#pragma unroll
  for (int j = 0; j < 6; ++j) {
    int o = w * 6 + j;
    bool isA = o < HH;
    int h = isA ? o : o - HH;
    const float* wr = (isA ? w_a : w_b) + (size_t)h * DD;
    float s = 0.f;
#pragma unroll
    for (int i = 0; i < 24; ++i) s = fmaf(xv[i], wr[lane + i * 64], s);
#pragma unroll
    for (int mm = 32; mm >= 1; mm >>= 1) s += __shfl_xor(s, mm, 64);
    if (lane == 0) {
      size_t idx = ((size_t)(b * HH + h) * TT + t) * 2;
      if (isA) {
        float a  = s + dt_bias[h];
        float sp = (a > 20.f) ? a : log1pf(expf(a));
        abi[idx] = expf(-expf(A_log[h]) * sp);
      } else {
        abi[idx + 1] = 2.f / (1.f + expf(-s));
      }
    }
  }
}

// ---------------------------------------------------------------------------
// Shared 64x64 MFMA GEMM helper (verified): C = X @ Y^T.
// ---------------------------------------------------------------------------
__device__ __forceinline__ void gemm64(
    const _Float16* XB, int xstr, const _Float16* YB, int ystr,
    int wr, int wc, int lane, int ksteps, int kpad, f32x4 acc[2][2])
{
#pragma unroll
  for (int m = 0; m < 2; ++m)
#pragma unroll
    for (int n = 0; n < 2; ++n)
#pragma unroll
      for (int j = 0; j < 4; ++j) acc[m][n][j] = 0.f;
#pragma unroll 4
  for (int kk = 0; kk < ksteps; ++kk) {
    const int koff = kk * 32 + ((kk >> 1) ? kpad : 0) + (lane >> 4) * 8;
    half8v a[2], b[2];
#pragma unroll
    for (int m = 0; m < 2; ++m)
      a[m] = *(const half8v*)(XB + (wr * 32 + m * 16 + (lane & 15)) * xstr + koff);
#pragma unroll
    for (int n = 0; n < 2; ++n)
      b[n] = *(const half8v*)(YB + (wc * 32 + n * 16 + (lane & 15)) * ystr + koff);
#pragma unroll
    for (int m = 0; m < 2; ++m)
#pragma unroll
      for (int n = 0; n < 2; ++n)
        acc[m][n] = __builtin_amdgcn_mfma_f32_16x16x32_f16(a[m], b[n], acc[m][n], 0, 0, 0);
  }
}

// ---------------------------------------------------------------------------
// Scan phase A (chunk-parallel, 384 blocks); f16 q/k/v inputs.
// ---------------------------------------------------------------------------
__global__ __launch_bounds__(256) void scan_phaseA(
    const ushort* __restrict__ qc, const ushort* __restrict__ kc,
    const ushort* __restrict__ vc, const float* __restrict__ abi,
    _Float16* __restrict__ SA, float* __restrict__ egCg)
{
  __shared__ _Float16 Kf[64 * 72];      // aliased as Tf after ph2
  __shared__ _Float16 Qf[64 * 72];
  __shared__ _Float16 KbT[64 * 72];     // [d][i] = betg_i k_i[d]
  __shared__ _Float16 VT[128 * 72];     // [v][t]
  __shared__ float    Af[64 * 67];
  __shared__ float    Tg[64 * 67];
  __shared__ float    tmpf[1088];
  __shared__ float    g_s[64], bet_s[64], betg_s[64], eg_s[64], eKs_s[64];
  _Float16* Tf = Kf;

  const int unit = blockIdx.x;
  const int bh   = unit % NBH;
  const int c    = unit / NBH;
  const int c0   = c * 64;
  const int tid  = threadIdx.x;
  const int lane = tid & 63;
  const int w    = tid >> 6;
  const int wr   = w >> 1, wc = w & 1;

  _Float16* SAu = SA + (size_t)unit * 24576;

  // ph0: scalars [bar]
  if (tid < 64) {
    float2 ab = *(const float2*)(abi + ((size_t)bh * TT + c0 + tid) * 2);
    float gg = logf(ab.x);
#pragma unroll
    for (int off = 1; off < 64; off <<= 1) {
      float up = __shfl_up(gg, off, 64);
      if (tid >= off) gg += up;
    }
    float gC = __shfl(gg, 63, 64);
    g_s[tid]    = gg;
    bet_s[tid]  = ab.y;
    betg_s[tid] = ab.y * expf(gg);
    eg_s[tid]   = expf(gg);
    eKs_s[tid]  = expf(gC - gg);
    if (tid == 0) egCg[unit] = expf(gC);
  }
  __syncthreads();

  // ph1: build Kf, KbT, Qf, VT; store Qg, KsT scratch; zero Tg [bar]
  {
    const int t  = tid >> 2;
    const int dg = tid & 3;
    const ushort* krow = kc + ((size_t)bh * TT + c0 + t) * 64 + dg * 16;
    const ushort* qrow = qc + ((size_t)bh * TT + c0 + t) * 64 + dg * 16;
    const float bg = betg_s[t], egt = eg_s[t], ekt = eKs_s[t];
    half8v kva = *(const half8v*)(krow), kvb = *(const half8v*)(krow + 8);
    half8v qva = *(const half8v*)(qrow), qvb = *(const half8v*)(qrow + 8);
#pragma unroll
    for (int e = 0; e < 8; ++e) {
      const int d = dg * 16 + e;
      const float kf = (float)kva[e], qf = (float)qva[e];
      Kf[t * 72 + d]              = kva[e];
      KbT[d * 72 + t]             = (_Float16)(kf * bg);
      Qf[t * 72 + d]              = qva[e];
      SAu[8192 + t * 64 + d]      = (_Float16)(qf * egt);   // Qg
      SAu[12288 + d * 64 + t]     = (_Float16)(kf * ekt);   // KsT [d][t]
    }
#pragma unroll
    for (int e = 0; e < 8; ++e) {
      const int d = dg * 16 + 8 + e;
      const float kf = (float)kvb[e], qf = (float)qvb[e];
      Kf[t * 72 + d]              = kvb[e];
      KbT[d * 72 + t]             = (_Float16)(kf * bg);
      Qf[t * 72 + d]              = qvb[e];
      SAu[8192 + t * 64 + d]      = (_Float16)(qf * egt);
      SAu[12288 + d * 64 + t]     = (_Float16)(kf * ekt);
    }
    const ushort* vrow = vc + ((size_t)bh * TT + c0 + t) * 128 + dg * 32;
    half8v v0 = *(const half8v*)(vrow),      v1 = *(const half8v*)(vrow + 8);
    half8v v2 = *(const half8v*)(vrow + 16), v3 = *(const half8v*)(vrow + 24);
#pragma unroll
    for (int e = 0; e < 8; ++e) {
      VT[(dg * 32 + e) * 72 + t]      = v0[e];
      VT[(dg * 32 + 8 + e) * 72 + t]  = v1[e];
      VT[(dg * 32 + 16 + e) * 72 + t] = v2[e];
      VT[(dg * 32 + 24 + e) * 72 + t] = v3[e];
    }
    for (int i = tid; i < 64 * 67; i += 256) Tg[i] = 0.f;
  }
  __syncthreads();

  // ph2: A = mask(beta e^dg K K^T) -> Af ; P = mask(e^dg Q K^T) -> scratch [bar]
  {
    f32x4 accA[2][2], accP[2][2];
    gemm64(Kf, 72, Kf, 72, wr, wc, lane, 2, 0, accA);
    gemm64(Qf, 72, Kf, 72, wr, wc, lane, 2, 0, accP);
#pragma unroll
    for (int m = 0; m < 2; ++m)
#pragma unroll
      for (int n = 0; n < 2; ++n)
#pragma unroll
        for (int j = 0; j < 4; ++j) {
          const int row = wr * 32 + m * 16 + (lane >> 4) * 4 + j;
          const int col = wc * 32 + n * 16 + (lane & 15);
          const float eg = expf(g_s[row] - g_s[col]);
          Af[row * 67 + col] = (col < row) ? bet_s[row] * eg * accA[m][n][j] : 0.f;
          SAu[4096 + row * 64 + col] =
              (col <= row) ? (_Float16)(eg * accP[m][n][j]) : (_Float16)0.f;
        }
  }
  __syncthreads();

  // ph3a: 4 diagonal 16x16 inverses into Tg [bar]
  if (lane < 16) {
    const int R = w * 16;
    Tg[R * 67 + R + lane] = (lane == 0) ? 1.f : 0.f;
    for (int t = 1; t < 16; ++t) {
      float s = 0.f;
      for (int i = 0; i < t; ++i)
        s = fmaf(Af[(R + t) * 67 + R + i], Tg[(R + i) * 67 + R + lane], s);
      Tg[(R + t) * 67 + R + lane] = ((lane == t) ? 1.f : 0.f) - s;
    }
  }
  __syncthreads();
  // ph3b-1 [bar]
  {
    const int r = (tid >> 4) & 15, cx = tid & 15;
#pragma unroll
    for (int p = 0; p < 2; ++p) {
      float s = 0.f;
      for (int i = 0; i < 16; ++i)
        s = fmaf(Af[(p * 32 + 16 + r) * 67 + p * 32 + i],
                 Tg[(p * 32 + i) * 67 + p * 32 + cx], s);
      tmpf[p * 272 + r * 17 + cx] = s;
    }
  }
  __syncthreads();
  // ph3b-2 [bar]
  {
    const int r = (tid >> 4) & 15, cx = tid & 15;
#pragma unroll
    for (int p = 0; p < 2; ++p) {
      float s = 0.f;
      for (int i = 0; i < 16; ++i)
        s = fmaf(Tg[(p * 32 + 16 + r) * 67 + p * 32 + 16 + i],
                 tmpf[p * 272 + i * 17 + cx], s);
      Tg[(p * 32 + 16 + r) * 67 + p * 32 + cx] = -s;
    }
  }
  __syncthreads();
  // ph3c-1 [bar]
  {
#pragma unroll
    for (int rep = 0; rep < 4; ++rep) {
      const int idx = tid + rep * 256;
      const int r = idx >> 5, cx = idx & 31;
      float s = 0.f;
      for (int i = 0; i < 32; ++i)
        s = fmaf(Af[(32 + r) * 67 + i], Tg[i * 67 + cx], s);
      tmpf[r * 33 + cx] = s;
    }
  }
  __syncthreads();
  // ph3c-2 [bar]
  {
#pragma unroll
    for (int rep = 0; rep < 4; ++rep) {
      const int idx = tid + rep * 256;
      const int r = idx >> 5, cx = idx & 31;
      float s = 0.f;
      for (int i = 0; i < 32; ++i)
        s = fmaf(Tg[(32 + r) * 67 + 32 + i], tmpf[i * 33 + cx], s);
      Tg[(32 + r) * 67 + cx] = -s;
    }
  }
  __syncthreads();

  // ph4: cast Tg -> Tf (aliases Kf; Kf dead after ph2) [bar]
  {
    const int t = tid >> 2, qg = tid & 3;
#pragma unroll
    for (int e = 0; e < 16; ++e) {
      const int i = qg * 16 + e;
      Tf[t * 72 + i] = (_Float16)Tg[t * 67 + i];
    }
  }
  __syncthreads();

  // ph5: W = T @ KbT^T -> scratch ; Z = T @ VT^T (two halves) -> scratch
  {
    f32x4 accW[2][2];
    gemm64(Tf, 72, KbT, 72, wr, wc, lane, 2, 0, accW);
#pragma unroll
    for (int m = 0; m < 2; ++m)
#pragma unroll
      for (int n = 0; n < 2; ++n)
#pragma unroll
        for (int j = 0; j < 4; ++j) {
          const int row = wr * 32 + m * 16 + (lane >> 4) * 4 + j;
          const int col = wc * 32 + n * 16 + (lane & 15);
          SAu[row * 64 + col] = (_Float16)accW[m][n][j];
        }
#pragma unroll
    for (int H = 0; H < 2; ++H) {
      f32x4 accZ[2][2];
      gemm64(Tf, 72, VT + H * 64 * 72, 72, wr, wc, lane, 2, 0, accZ);
#pragma unroll
      for (int m = 0; m < 2; ++m)
#pragma unroll
        for (int n = 0; n < 2; ++n)
#pragma unroll
          for (int j = 0; j < 4; ++j) {
            const int row = wr * 32 + m * 16 + (lane >> 4) * 4 + j;
            const int col = wc * 32 + n * 16 + (lane & 15);
            SAu[16384 + row * 128 + H * 64 + col] = (_Float16)accZ[m][n][j];
          }
    }
  }
}

// ---------------------------------------------------------------------------
// Scan phase B (serial over 16 chunks; 48 blocks = bh x 2 v-halves): pure
// scratch consumer (R18-proven form).
// ---------------------------------------------------------------------------
__global__ __launch_bounds__(256) void scan_phaseB(
    const _Float16* __restrict__ SA, const float* __restrict__ egCg,
    float* __restrict__ o)
{
  __shared__ float    Sf[64 * 65];      // S^T half [v][d] f32 (persistent)
  __shared__ _Float16 Wl[64 * 72];      // [t][d]
  __shared__ _Float16 KsTl[64 * 72];    // [d][t]
  __shared__ _Float16 Zl[64 * 72];      // [t][v-half]
  __shared__ _Float16 X2[64 * 144];     // [t][0:64]=Qg, [72:136]=P
  __shared__ _Float16 Y2[64 * 144];     // [v][0:64]=S0^T f16, [72:136]=U^T

  const int blk  = blockIdx.x;
  const int bh   = blk % NBH;
  const int H    = blk / NBH;           // 0..1 (v half)
  const int b    = bh / HH, h = bh % HH;
  const int tid  = threadIdx.x;
  const int lane = tid & 63;
  const int w    = tid >> 6;
  const int wr   = w >> 1, wc = w & 1;

  for (int i = tid; i < 64 * 65; i += 256) Sf[i] = 0.f;
  __syncthreads();

  for (int c = 0; c < TT / 64; ++c) {
    const int c0   = c * 64;
    const size_t u = (size_t)(c * NBH + bh);
    const ushort* base = (const ushort*)(SA + u * 24576);
    const float egC = egCg[u];

    // b1: load 5 matrices to LDS; cast Sf -> Y2-left [bar]
    {
#pragma unroll
      for (int r = 0; r < 2; ++r) {
        const int idx = tid + r * 256;       // 0..511
        const int row = idx >> 3, c8 = idx & 7;
        *(uint4*)((ushort*)Wl + row * 72 + c8 * 8) =
            *(const uint4*)(base + idx * 8);                       // W
        *(uint4*)((ushort*)X2 + row * 144 + 72 + c8 * 8) =
            *(const uint4*)(base + 4096 + idx * 8);                // P
        *(uint4*)((ushort*)X2 + row * 144 + c8 * 8) =
            *(const uint4*)(base + 8192 + idx * 8);                // Qg
        *(uint4*)((ushort*)KsTl + row * 72 + c8 * 8) =
            *(const uint4*)(base + 12288 + idx * 8);               // KsT
        *(uint4*)((ushort*)Zl + row * 72 + c8 * 8) =
            *(const uint4*)(base + 16384 + row * 128 + H * 64 + c8 * 8);  // Z half
      }
      const int v = tid >> 2, ds = tid & 3;
#pragma unroll
      for (int e = 0; e < 16; ++e)
        Y2[v * 144 + ds * 16 + e] = (_Float16)Sf[v * 65 + ds * 16 + e];
    }
    __syncthreads();

    // b2: U = Z - W @ S0 -> Y2-right [bar]
    {
      f32x4 accU[2][2];
      gemm64(Wl, 72, Y2, 144, wr, wc, lane, 2, 0, accU);
#pragma unroll
      for (int m = 0; m < 2; ++m)
#pragma unroll
        for (int n = 0; n < 2; ++n)
#pragma unroll
          for (int j = 0; j < 4; ++j) {
            const int row = wr * 32 + m * 16 + (lane >> 4) * 4 + j;  // t
            const int col = wc * 32 + n * 16 + (lane & 15);          // v
            const float uval = (float)Zl[row * 72 + col] - accU[m][n][j];
            Y2[col * 144 + 72 + row] = (_Float16)uval;
          }
    }
    __syncthreads();

    // b3: S = egC*S + KsT@U ; O = [Qg|P]@[S0^T|U^T]^T -> o [bar]
    {
      f32x4 accS[2][2], accO[2][2];
      gemm64(KsTl, 72, Y2 + 72, 144, wr, wc, lane, 2, 0, accS);
      gemm64(X2, 144, Y2, 144, wr, wc, lane, 4, 8, accO);
#pragma unroll
      for (int m = 0; m < 2; ++m)
#pragma unroll
        for (int n = 0; n < 2; ++n)
#pragma unroll
          for (int j = 0; j < 4; ++j) {
            const int row = wr * 32 + m * 16 + (lane >> 4) * 4 + j;  // d (S) / t (O)
            const int col = wc * 32 + n * 16 + (lane & 15);          // v
            Sf[col * 65 + row] = egC * Sf[col * 65 + row] + accS[m][n][j];
            o[(((size_t)b * TT + c0 + row) * HH + h) * 128 + H * 64 + col] = accO[m][n][j];
          }
    }
    __syncthreads();
  }
}

// ---------------------------------------------------------------------------
// RMS norm over 128 + SiLU gate; reads f16 g16; emits fp16 for final GEMM.
// ---------------------------------------------------------------------------
__global__ void rmsgate_kernel(const float* __restrict__ o, const ushort* __restrict__ g16,
                               ushort* __restrict__ gof)
{
  int gid  = blockIdx.x * blockDim.x + threadIdx.x;
  int wid  = gid >> 6;
  int lane = threadIdx.x & 63;
  if (wid >= BB * TT * HH) return;
  int h = wid % HH;
  int m = wid / HH;
  const float* orow = o + (size_t)wid * 128;
  float2 ov = *(const float2*)(orow + lane * 2);
  float ss = ov.x * ov.x + ov.y * ov.y;
#pragma unroll
  for (int mm = 32; mm >= 1; mm >>= 1) ss += __shfl_xor(ss, mm, 64);
  float scale = rsqrtf(ss * (1.f / 128.f) + EPSF);
  const ushort* gr = g16 + (size_t)m * TVv + h * 128 + lane * 2;
  float o0 = ov.x * scale * siluf(h2f(gr[0]));
  float o1 = ov.y * scale * siluf(h2f(gr[1]));
  *(uint*)(gof + (size_t)m * TVv + h * 128 + lane * 2) = pk2h(o0, o1);
}

// ---------------------------------------------------------------------------
extern "C" void kernel_launch(void* const* d_in, const int* in_sizes, int n_in,
                              void* d_out, int out_size, void* d_ws, size_t ws_size,
                              hipStream_t stream) {
  (void)in_sizes; (void)n_in; (void)out_size; (void)ws_size;
  const float* x       = (const float*)d_in[0];
  const float* w_q     = (const float*)d_in[1];
  const float* w_k     = (const float*)d_in[2];
  const float* w_v     = (const float*)d_in[3];
  const float* w_a     = (const float*)d_in[4];
  const float* w_b     = (const float*)d_in[5];
  const float* w_g     = (const float*)d_in[6];
  const float* w_out   = (const float*)d_in[7];
  const float* A_log   = (const float*)d_in[8];
  const float* dt_bias = (const float*)d_in[9];
  const float* qcw     = (const float*)d_in[10];
  const float* kcw     = (const float*)d_in[11];
  const float* vcw     = (const float*)d_in[12];

  // Workspace (63.11 MB), time-multiplexed (all lifetimes audited):
  //  Region A [0..9437184)f : pA+pB (big-gemm f16 partials)
  //                           -> SA (4718592f) + egCg + o + woutf
  //                           -> fp4 (final-gemm partials, [0..6291456)f)
  //  Cu [9437184..15728640)f: xf+wcat -> qc16/kc16/vc16 + g16 + gof
  //  abi [15728640..15777792)f
  float* ws  = (float*)d_ws;
  float* abi = ws + 15728640;

  ushort* xf    = (ushort*)(ws + 9437184);
  ushort* wcat  = (ushort*)(ws + 9437184 + 1572864);

  ushort* pA = (ushort*)ws;                        // 2048*4608 f16
  ushort* pB = (ushort*)(ws + 4718592);

  ushort* qc16 = (ushort*)(ws + 9437184);          // 2048*12*64*... = 1572864 ush
  ushort* kc16 = (ushort*)(ws + 9437184 + 786432);
  ushort* vc16 = (ushort*)(ws + 9437184 + 1572864);
  ushort* g16  = (ushort*)(ws + 9437184 + 3145728);
  ushort* gof  = (ushort*)(ws + 9437184 + 4718592);

  _Float16* SA   = (_Float16*)ws;                  // 384*24576 f16
  float*    egCg = ws + 4718592;                   // 384 floats
  float*    o    = ws + 4719104;                   // 3145728 floats
  ushort*   woutf = (ushort*)(ws + 7864832);       // 2359296 ushorts
  ushort*   fp4   = (ushort*)ws;                   // 4 * 3145728 ushorts

  const int M = BB * TT;  // 2048
  dim3 blk(256);

  // 1) fp16 casts
  cast_f16_kernel<<<1536, blk, 0, stream>>>(x, xf);
  cast_w4_kernel<<<3456, blk, 0, stream>>>(w_q, w_k, w_v, w_g, wcat);

  // 2) fused qkv+g projection, K-split-2 -> f16 partials (1152 blocks)
  gemm_f16_ks<<<dim3(NQKVG / 128, M / 128, 2), blk, 0, stream>>>(
      xf, wcat, pA, M, NQKVG, DD, DD / 2);

  // 3) gating coefficients
  gate_kernel<<<M, blk, 0, stream>>>(x, w_a, w_b, A_log, dt_bias, abi);

  // 4) conv + SiLU + L2 norm (consumes both partials; f16 outputs)
  conv_silu_kernel<<<24576, blk, 0, stream>>>(pA, pB, qcw, kcw, vcw, qc16, kc16, vc16);

  // 5) fold g-columns of partials -> g16
  gsum16_kernel<<<1536, blk, 0, stream>>>(pA, pB, g16);

  // 6) scan: chunk-parallel phase A, serial phase B
  scan_phaseA<<<16 * NBH, blk, 0, stream>>>(qc16, kc16, vc16, abi, SA, egCg);
  scan_phaseB<<<2 * NBH, blk, 0, stream>>>(SA, egCg, o);

  // 7) cast w_out
  cast_f16_kernel<<<1152, blk, 0, stream>>>(w_out, woutf);

  // 8) RMS norm + SiLU gate -> gof
  rmsgate_kernel<<<6144, blk, 0, stream>>>(o, g16, gof);

  // 9) output projection, K-split-4 -> f16 partials (768 blocks)
  gemm_f16_ks<<<dim3(TVv / 128, M / 128, 4), blk, 0, stream>>>(
      gof, woutf, fp4, M, TVv, DD, DD / 4);

  // 10) reduce partials -> d_out
  reduce4_kernel<<<1536, blk, 0, stream>>>(fp4, (float*)d_out);
}

// Round 23
// 214.147 us; speedup vs baseline: 1.1966x; 1.0277x over previous
//
#include <hip/hip_runtime.h>
#include <math.h>

#define BB 2
#define TT 1024
#define DD 1536
#define HH 12
#define TQK 768
#define TVv 1536
#define CQKV 3072
#define NQKVG 4608
#define EPSF 1e-6f
#define NBH (BB * HH)   // 24

// scratch swizzle: row-linear, 16B chunks XOR'd by row&7 (conflict-free b128)
#define SWZ(row, col) ((row) * 64 + ((((col) >> 3) ^ ((row) & 7)) << 3) + ((col) & 7))

typedef __attribute__((ext_vector_type(8))) _Float16 half8v;
typedef __attribute__((ext_vector_type(4))) float f32x4;

__device__ __forceinline__ float siluf(float x) { return x / (1.f + expf(-x)); }

__device__ __forceinline__ uint pk2h(float a, float b) {
  union { _Float16 h[2]; uint u; } p;
  p.h[0] = (_Float16)a; p.h[1] = (_Float16)b;
  return p.u;
}
__device__ __forceinline__ ushort f2h(float f) {
  _Float16 h = (_Float16)f; ushort u; __builtin_memcpy(&u, &h, 2); return u;
}
__device__ __forceinline__ float h2f(ushort u) {
  _Float16 h; __builtin_memcpy(&h, &u, 2); return (float)h;
}

// async global->LDS
__device__ __forceinline__ void gload16(const void* g, void* l) {
  __builtin_amdgcn_global_load_lds(
      (const __attribute__((address_space(1))) void*)g,
      (__attribute__((address_space(3))) void*)l, 16, 0, 0);
}

// ---------------------------------------------------------------------------
// fp16 MFMA GEMM, K-SPLIT (R22-proven).
// ---------------------------------------------------------------------------
__global__ __launch_bounds__(256) void gemm_f16_ks(
    const ushort* __restrict__ X, const ushort* __restrict__ W,
    ushort* __restrict__ P, int M, int N, int K, int KS)
{
  __shared__ ushort Ah[128 * 64];
  __shared__ ushort Bh[128 * 64];
  const int tid  = threadIdx.x;
  const int lane = tid & 63;
  const int w    = tid >> 6;
  const int wr   = w >> 1, wc = w & 1;
  const int r0   = blockIdx.y * 128, c0 = blockIdx.x * 128;
  const int k0b  = blockIdx.z * KS;
  ushort* Pz = P + (size_t)blockIdx.z * M * N;

  const int dr   = lane >> 3;
  const int slot = (lane & 7) ^ dr;

  f32x4 acc[4][4];
#pragma unroll
  for (int m = 0; m < 4; ++m)
#pragma unroll
    for (int n = 0; n < 4; ++n)
#pragma unroll
      for (int j = 0; j < 4; ++j) acc[m][n][j] = 0.f;

  for (int k0 = k0b; k0 < k0b + KS; k0 += 64) {
#pragma unroll
    for (int j = 0; j < 4; ++j) {
      const int row  = (w * 4 + j) * 8 + dr;
      const size_t xo = (size_t)(r0 + row) * K + k0 + slot * 8;
      const size_t wo = (size_t)(c0 + row) * K + k0 + slot * 8;
      const int ldso = (w * 4 + j) * 512;
      gload16(X + xo, Ah + ldso);
      gload16(W + wo, Bh + ldso);
    }
    __syncthreads();
#pragma unroll
    for (int kk = 0; kk < 2; ++kk) {
      const int kc8 = kk * 4 + (lane >> 4);
      const int sw  = (kc8 ^ (lane & 7)) << 3;
      half8v a[4], b[4];
#pragma unroll
      for (int m = 0; m < 4; ++m)
        a[m] = *(const half8v*)(Ah + (wr * 64 + m * 16 + (lane & 15)) * 64 + sw);
#pragma unroll
      for (int n = 0; n < 4; ++n)
        b[n] = *(const half8v*)(Bh + (wc * 64 + n * 16 + (lane & 15)) * 64 + sw);
#pragma unroll
      for (int m = 0; m < 4; ++m)
#pragma unroll
        for (int n = 0; n < 4; ++n)
          acc[m][n] = __builtin_amdgcn_mfma_f32_16x16x32_f16(a[m], b[n], acc[m][n], 0, 0, 0);
    }
    __syncthreads();
  }

  const int crow = (lane >> 4) * 4;
  const int ccol = lane & 15;
#pragma unroll
  for (int m = 0; m < 4; ++m)
#pragma unroll
    for (int j = 0; j < 4; ++j) {
      ushort* cp = Pz + (size_t)(r0 + wr * 64 + m * 16 + crow + j) * N + c0 + wc * 64 + ccol;
#pragma unroll
      for (int n = 0; n < 4; ++n) cp[n * 16] = f2h(acc[m][n][j]);
    }
}

// ---------------------------------------------------------------------------
// f32 -> fp16 casts.
// ---------------------------------------------------------------------------
__device__ __forceinline__ void cast8_store(const float* f, ushort* dst, size_t e)
{
  uint4 pk;
  pk.x = pk2h(f[0], f[1]); pk.y = pk2h(f[2], f[3]);
  pk.z = pk2h(f[4], f[5]); pk.w = pk2h(f[6], f[7]);
  *(uint4*)(dst + e) = pk;
}

__global__ void cast_f16_kernel(const float* __restrict__ src, ushort* __restrict__ dst)
{
  int cid = blockIdx.x * blockDim.x + threadIdx.x;
  size_t e = (size_t)cid * 8;
  float f[8];
  *(float4*)(f)     = *(const float4*)(src + e);
  *(float4*)(f + 4) = *(const float4*)(src + e + 4);
  cast8_store(f, dst, e);
}

__global__ void cast_w4_kernel(const float* __restrict__ wq, const float* __restrict__ wk,
                               const float* __restrict__ wv, const float* __restrict__ wg,
                               ushort* __restrict__ dst)
{
  int cid = blockIdx.x * blockDim.x + threadIdx.x;
  size_t e = (size_t)cid * 8;
  const float* src; size_t off;
  if (e < 1179648)      { src = wq; off = e; }
  else if (e < 2359296) { src = wk; off = e - 1179648; }
  else if (e < 4718592) { src = wv; off = e - 2359296; }
  else                  { src = wg; off = e - 4718592; }
  float f[8];
  *(float4*)(f)     = *(const float4*)(src + off);
  *(float4*)(f + 4) = *(const float4*)(src + off + 4);
  cast8_store(f, dst, e);
}

// ---------------------------------------------------------------------------
// Causal depthwise conv (K=4) + SiLU + fused L2-norm (f16 partial inputs).
// ---------------------------------------------------------------------------
__global__ void conv_silu_kernel(
    const ushort* __restrict__ pA, const ushort* __restrict__ pB,
    const float* __restrict__ qw, const float* __restrict__ kw, const float* __restrict__ vw,
    ushort* __restrict__ qc, ushort* __restrict__ kc, ushort* __restrict__ vc)
{
  int idx = blockIdx.x * blockDim.x + threadIdx.x;
  int c  = idx % CQKV;
  int bt = idx / CQKV;
  int t  = bt % TT;
  int b  = bt / TT;

  const float* wp;
  if (c < TQK)          wp = qw + (size_t)c * 4;
  else if (c < 2 * TQK) wp = kw + (size_t)(c - TQK) * 4;
  else                  wp = vw + (size_t)(c - 2 * TQK) * 4;

  float s = 0.f;
#pragma unroll
  for (int j = 0; j < 4; ++j) {
    int ts = t - 3 + j;
    if (ts >= 0) {
      size_t ii = (size_t)(b * TT + ts) * NQKVG + c;
      float v = h2f(pA[ii]) + h2f(pB[ii]);
      s = fmaf(v, wp[j], s);
    }
  }
  s = siluf(s);

  if (c < 2 * TQK) {
    float ss = s * s;
#pragma unroll
    for (int m = 32; m >= 1; m >>= 1) ss += __shfl_xor(ss, m, 64);
    s = s / fmaxf(sqrtf(ss), EPSF);
  }

  if (c < TQK) {
    int h = c >> 6, d = c & 63;
    qc[((size_t)(b * HH + h) * TT + t) * 64 + d] = f2h(s);
  } else if (c < 2 * TQK) {
    int c2 = c - TQK; int h = c2 >> 6, d = c2 & 63;
    kc[((size_t)(b * HH + h) * TT + t) * 64 + d] = f2h(s);
  } else {
    int c2 = c - 2 * TQK; int h = c2 >> 7, d = c2 & 127;
    vc[((size_t)(b * HH + h) * TT + t) * 128 + d] = f2h(s);
  }
}

// ---------------------------------------------------------------------------
// gsum16: fold g-columns of the two big-GEMM partials into compact g16.
// ---------------------------------------------------------------------------
__global__ void gsum16_kernel(const ushort* __restrict__ pA, const ushort* __restrict__ pB,
                              ushort* __restrict__ g16)
{
  int cid = blockIdx.x * blockDim.x + threadIdx.x;
  int e   = cid * 8;
  int m   = e / TVv, j = e % TVv;
  size_t src = (size_t)m * NQKVG + CQKV + j;
  half8v a = *(const half8v*)(pA + src);
  half8v b = *(const half8v*)(pB + src);
  half8v r;
#pragma unroll
  for (int i = 0; i < 8; ++i) r[i] = (_Float16)((float)a[i] + (float)b[i]);
  *(half8v*)(g16 + e) = r;
}

// ---------------------------------------------------------------------------
// reduce4: d_out = sum of 4 f16 partials of the final GEMM.
// ---------------------------------------------------------------------------
__global__ void reduce4_kernel(const ushort* __restrict__ p, float* __restrict__ out)
{
  int cid = blockIdx.x * blockDim.x + threadIdx.x;
  size_t e = (size_t)cid * 8;
  float acc8[8];
#pragma unroll
  for (int i = 0; i < 8; ++i) acc8[i] = 0.f;
#pragma unroll
  for (int part = 0; part < 4; ++part) {
    half8v v = *(const half8v*)(p + (size_t)part * 3145728 + e);
#pragma unroll
    for (int i = 0; i < 8; ++i) acc8[i] += (float)v[i];
  }
  *(float4*)(out + e)     = make_float4(acc8[0], acc8[1], acc8[2], acc8[3]);
  *(float4*)(out + e + 4) = make_float4(acc8[4], acc8[5], acc8[6], acc8[7]);
}

// ---------------------------------------------------------------------------
// Gating: block per row; writes interleaved (alpha,beta).
// ---------------------------------------------------------------------------
__global__ __launch_bounds__(256) void gate_kernel(
    const float* __restrict__ x, const float* __restrict__ w_a, const float* __restrict__ w_b,
    const float* __restrict__ A_log, const float* __restrict__ dt_bias,
    float* __restrict__ abi)
{
  const int m    = blockIdx.x;
  const int w    = threadIdx.x >> 6;
  const int lane = threadIdx.x & 63;
  const float* xr = x + (size_t)m * DD;
  float xv[24];
#pragma unroll
  for (int i = 0; i < 24; ++i) xv[i] = xr[lane + i * 64];
  const int b = m / TT, t = m % TT;
#pragma unroll
  for (int j = 0; j < 6; ++j) {
    int o = w * 6 + j;
    bool isA = o < HH;
    int h = isA ? o : o - HH;
    const float* wr = (isA ? w_a : w_b) + (size_t)h * DD;
    float s = 0.f;
#pragma unroll
    for (int i = 0; i < 24; ++i) s = fmaf(xv[i], wr[lane + i * 64], s);
#pragma unroll
    for (int mm = 32; mm >= 1; mm >>= 1) s += __shfl_xor(s, mm, 64);
    if (lane == 0) {
      size_t idx = ((size_t)(b * HH + h) * TT + t) * 2;
      if (isA) {
        float a  = s + dt_bias[h];
        float sp = (a > 20.f) ? a : log1pf(expf(a));
        abi[idx] = expf(-expf(A_log[h]) * sp);
      } else {
        abi[idx + 1] = 2.f / (1.f + expf(-s));
      }
    }
  }
}

// ---------------------------------------------------------------------------
// Shared 64x64 MFMA GEMM helper (stride-padded LDS): C = X @ Y^T.
// ---------------------------------------------------------------------------
__device__ __forceinline__ void gemm64(
    const _Float16* XB, int xstr, const _Float16* YB, int ystr,
    int wr, int wc, int lane, int ksteps, int kpad, f32x4 acc[2][2])
{
#pragma unroll
  for (int m = 0; m < 2; ++m)
#pragma unroll
    for (int n = 0; n < 2; ++n)
#pragma unroll
      for (int j = 0; j < 4; ++j) acc[m][n][j] = 0.f;
#pragma unroll 4
  for (int kk = 0; kk < ksteps; ++kk) {
    const int koff = kk * 32 + ((kk >> 1) ? kpad : 0) + (lane >> 4) * 8;
    half8v a[2], b[2];
#pragma unroll
    for (int m = 0; m < 2; ++m)
      a[m] = *(const half8v*)(XB + (wr * 32 + m * 16 + (lane & 15)) * xstr + koff);
#pragma unroll
    for (int n = 0; n < 2; ++n)
      b[n] = *(const half8v*)(YB + (wc * 32 + n * 16 + (lane & 15)) * ystr + koff);
#pragma unroll
    for (int m = 0; m < 2; ++m)
#pragma unroll
      for (int n = 0; n < 2; ++n)
        acc[m][n] = __builtin_amdgcn_mfma_f32_16x16x32_f16(a[m], b[n], acc[m][n], 0, 0, 0);
  }
}

// Swizzled-X variant (stride-64 XOR layout), Y from Y2 (stride ystr).
// ACCUMULATES into acc (caller zeroes).
__device__ __forceinline__ void gemm64x(
    const ushort* XB, const _Float16* YB, int ystr,
    int wr, int wc, int lane, f32x4 acc[2][2])
{
#pragma unroll
  for (int kk = 0; kk < 2; ++kk) {
    const int cl = kk * 4 + (lane >> 4);
    half8v a[2], b[2];
#pragma unroll
    for (int m = 0; m < 2; ++m) {
      const int row = wr * 32 + m * 16 + (lane & 15);
      a[m] = *(const half8v*)((const _Float16*)XB + row * 64 + ((cl ^ (row & 7)) << 3));
    }
#pragma unroll
    for (int n = 0; n < 2; ++n)
      b[n] = *(const half8v*)(YB + (wc * 32 + n * 16 + (lane & 15)) * ystr + kk * 32 + (lane >> 4) * 8);
#pragma unroll
    for (int m = 0; m < 2; ++m)
#pragma unroll
      for (int n = 0; n < 2; ++n)
        acc[m][n] = __builtin_amdgcn_mfma_f32_16x16x32_f16(a[m], b[n], acc[m][n], 0, 0, 0);
  }
}

// ---------------------------------------------------------------------------
// Scan phase A (chunk-parallel, 384 blocks); writes scratch in the SWZ
// row-linear layout: unit = [W | P | Qg | KsT | Z0 | Z1], 4096 ush each.
// ---------------------------------------------------------------------------
__global__ __launch_bounds__(256) void scan_phaseA(
    const ushort* __restrict__ qc, const ushort* __restrict__ kc,
    const ushort* __restrict__ vc, const float* __restrict__ abi,
    _Float16* __restrict__ SA, float* __restrict__ egCg)
{
  __shared__ _Float16 Kf[64 * 72];      // aliased as Tf after ph2
  __shared__ _Float16 Qf[64 * 72];
  __shared__ _Float16 KbT[64 * 72];
  __shared__ _Float16 VT[128 * 72];
  __shared__ float    Af[64 * 67];
  __shared__ float    Tg[64 * 67];
  __shared__ float    tmpf[1088];
  __shared__ float    g_s[64], bet_s[64], betg_s[64], eg_s[64], eKs_s[64];
  _Float16* Tf = Kf;

  const int unit = blockIdx.x;
  const int bh   = unit % NBH;
  const int c    = unit / NBH;
  const int c0   = c * 64;
  const int tid  = threadIdx.x;
  const int lane = tid & 63;
  const int w    = tid >> 6;
  const int wr   = w >> 1, wc = w & 1;

  _Float16* SAu = SA + (size_t)unit * 24576;

  if (tid < 64) {
    float2 ab = *(const float2*)(abi + ((size_t)bh * TT + c0 + tid) * 2);
    float gg = logf(ab.x);
#pragma unroll
    for (int off = 1; off < 64; off <<= 1) {
      float up = __shfl_up(gg, off, 64);
      if (tid >= off) gg += up;
    }
    float gC = __shfl(gg, 63, 64);
    g_s[tid]    = gg;
    bet_s[tid]  = ab.y;
    betg_s[tid] = ab.y * expf(gg);
    eg_s[tid]   = expf(gg);
    eKs_s[tid]  = expf(gC - gg);
    if (tid == 0) egCg[unit] = expf(gC);
  }
  __syncthreads();

  // ph1
  {
    const int t  = tid >> 2;
    const int dg = tid & 3;
    const ushort* krow = kc + ((size_t)bh * TT + c0 + t) * 64 + dg * 16;
    const ushort* qrow = qc + ((size_t)bh * TT + c0 + t) * 64 + dg * 16;
    const float bg = betg_s[t], egt = eg_s[t], ekt = eKs_s[t];
    half8v kva = *(const half8v*)(krow), kvb = *(const half8v*)(krow + 8);
    half8v qva = *(const half8v*)(qrow), qvb = *(const half8v*)(qrow + 8);
#pragma unroll
    for (int e = 0; e < 8; ++e) {
      const int d = dg * 16 + e;
      const float kf = (float)kva[e], qf = (float)qva[e];
      Kf[t * 72 + d]              = kva[e];
      KbT[d * 72 + t]             = (_Float16)(kf * bg);
      Qf[t * 72 + d]              = qva[e];
      SAu[8192 + SWZ(t, d)]       = (_Float16)(qf * egt);   // Qg
      SAu[12288 + SWZ(d, t)]      = (_Float16)(kf * ekt);   // KsT
    }
#pragma unroll
    for (int e = 0; e < 8; ++e) {
      const int d = dg * 16 + 8 + e;
      const float kf = (float)kvb[e], qf = (float)qvb[e];
      Kf[t * 72 + d]              = kvb[e];
      KbT[d * 72 + t]             = (_Float16)(kf * bg);
      Qf[t * 72 + d]              = qvb[e];
      SAu[8192 + SWZ(t, d)]       = (_Float16)(qf * egt);
      SAu[12288 + SWZ(d, t)]      = (_Float16)(kf * ekt);
    }
    const ushort* vrow = vc + ((size_t)bh * TT + c0 + t) * 128 + dg * 32;
    half8v v0 = *(const half8v*)(vrow),      v1 = *(const half8v*)(vrow + 8);
    half8v v2 = *(const half8v*)(vrow + 16), v3 = *(const half8v*)(vrow + 24);
#pragma unroll
    for (int e = 0; e < 8; ++e) {
      VT[(dg * 32 + e) * 72 + t]      = v0[e];
      VT[(dg * 32 + 8 + e) * 72 + t]  = v1[e];
      VT[(dg * 32 + 16 + e) * 72 + t] = v2[e];
      VT[(dg * 32 + 24 + e) * 72 + t] = v3[e];
    }
    for (int i = tid; i < 64 * 67; i += 256) Tg[i] = 0.f;
  }
  __syncthreads();

  // ph2: A and P
  {
    f32x4 accA[2][2], accP[2][2];
    gemm64(Kf, 72, Kf, 72, wr, wc, lane, 2, 0, accA);
    gemm64(Qf, 72, Kf, 72, wr, wc, lane, 2, 0, accP);
#pragma unroll
    for (int m = 0; m < 2; ++m)
#pragma unroll
      for (int n = 0; n < 2; ++n)
#pragma unroll
        for (int j = 0; j < 4; ++j) {
          const int row = wr * 32 + m * 16 + (lane >> 4) * 4 + j;
          const int col = wc * 32 + n * 16 + (lane & 15);
          const float eg = expf(g_s[row] - g_s[col]);
          Af[row * 67 + col] = (col < row) ? bet_s[row] * eg * accA[m][n][j] : 0.f;
          SAu[4096 + SWZ(row, col)] =
              (col <= row) ? (_Float16)(eg * accP[m][n][j]) : (_Float16)0.f;
        }
  }
  __syncthreads();

  // ph3a
  if (lane < 16) {
    const int R = w * 16;
    Tg[R * 67 + R + lane] = (lane == 0) ? 1.f : 0.f;
    for (int t = 1; t < 16; ++t) {
      float s = 0.f;
      for (int i = 0; i < t; ++i)
        s = fmaf(Af[(R + t) * 67 + R + i], Tg[(R + i) * 67 + R + lane], s);
      Tg[(R + t) * 67 + R + lane] = ((lane == t) ? 1.f : 0.f) - s;
    }
  }
  __syncthreads();
  // ph3b-1
  {
    const int r = (tid >> 4) & 15, cx = tid & 15;
#pragma unroll
    for (int p = 0; p < 2; ++p) {
      float s = 0.f;
      for (int i = 0; i < 16; ++i)
        s = fmaf(Af[(p * 32 + 16 + r) * 67 + p * 32 + i],
                 Tg[(p * 32 + i) * 67 + p * 32 + cx], s);
      tmpf[p * 272 + r * 17 + cx] = s;
    }
  }
  __syncthreads();
  // ph3b-2
  {
    const int r = (tid >> 4) & 15, cx = tid & 15;
#pragma unroll
    for (int p = 0; p < 2; ++p) {
      float s = 0.f;
      for (int i = 0; i < 16; ++i)
        s = fmaf(Tg[(p * 32 + 16 + r) * 67 + p * 32 + 16 + i],
                 tmpf[p * 272 + i * 17 + cx], s);
      Tg[(p * 32 + 16 + r) * 67 + p * 32 + cx] = -s;
    }
  }
  __syncthreads();
  // ph3c-1
  {
#pragma unroll
    for (int rep = 0; rep < 4; ++rep) {
      const int idx = tid + rep * 256;
      const int r = idx >> 5, cx = idx & 31;
      float s = 0.f;
      for (int i = 0; i < 32; ++i)
        s = fmaf(Af[(32 + r) * 67 + i], Tg[i * 67 + cx], s);
      tmpf[r * 33 + cx] = s;
    }
  }
  __syncthreads();
  // ph3c-2
  {
#pragma unroll
    for (int rep = 0; rep < 4; ++rep) {
      const int idx = tid + rep * 256;
      const int r = idx >> 5, cx = idx & 31;
      float s = 0.f;
      for (int i = 0; i < 32; ++i)
        s = fmaf(Tg[(32 + r) * 67 + 32 + i], tmpf[i * 33 + cx], s);
      Tg[(32 + r) * 67 + cx] = -s;
    }
  }
  __syncthreads();

  // ph4: cast Tg -> Tf
  {
    const int t = tid >> 2, qg = tid & 3;
#pragma unroll
    for (int e = 0; e < 16; ++e) {
      const int i = qg * 16 + e;
      Tf[t * 72 + i] = (_Float16)Tg[t * 67 + i];
    }
  }
  __syncthreads();

  // ph5: W, Z -> scratch (SWZ layout)
  {
    f32x4 accW[2][2];
    gemm64(Tf, 72, KbT, 72, wr, wc, lane, 2, 0, accW);
#pragma unroll
    for (int m = 0; m < 2; ++m)
#pragma unroll
      for (int n = 0; n < 2; ++n)
#pragma unroll
        for (int j = 0; j < 4; ++j) {
          const int row = wr * 32 + m * 16 + (lane >> 4) * 4 + j;
          const int col = wc * 32 + n * 16 + (lane & 15);
          SAu[SWZ(row, col)] = (_Float16)accW[m][n][j];
        }
#pragma unroll
    for (int H = 0; H < 2; ++H) {
      f32x4 accZ[2][2];
      gemm64(Tf, 72, VT + H * 64 * 72, 72, wr, wc, lane, 2, 0, accZ);
#pragma unroll
      for (int m = 0; m < 2; ++m)
#pragma unroll
        for (int n = 0; n < 2; ++n)
#pragma unroll
          for (int j = 0; j < 4; ++j) {
            const int row = wr * 32 + m * 16 + (lane >> 4) * 4 + j;
            const int col = wc * 32 + n * 16 + (lane & 15);
            SAu[16384 + H * 4096 + SWZ(row, col)] = (_Float16)accZ[m][n][j];
          }
    }
  }
}

// ---------------------------------------------------------------------------
// Scan phase B: serial over 16 chunks; 48 blocks = bh x 2 v-halves.
// Double-buffered LDS scratch via global_load_lds (linear dest, SWZ-stored
// source) with COUNTED vmcnt: STAGE(c+1) at chunk-c start stays in flight
// over the whole chunk; raw barriers (lgkmcnt(0), never vmcnt(0) in-loop).
// ---------------------------------------------------------------------------
__global__ __launch_bounds__(256) void scan_phaseB(
    const _Float16* __restrict__ SA, const float* __restrict__ egCg,
    float* __restrict__ o)
{
  __shared__ float    Sf[64 * 65];      // S^T half [v][d] f32 (persistent)
  __shared__ ushort   B0[20480];        // [W|P|Qg|KsT|Zhalf] x 4096 ush
  __shared__ ushort   B1[20480];
  __shared__ _Float16 Y2[64 * 144];     // [v][0:64]=S0^T, [72:136]=U^T
  __shared__ float    egc_l[16];

  const int blk  = blockIdx.x;
  const int bh   = blk % NBH;
  const int H    = blk / NBH;
  const int b    = bh / HH, h = bh % HH;
  const int tid  = threadIdx.x;
  const int lane = tid & 63;
  const int w    = tid >> 6;
  const int wr   = w >> 1, wc = w & 1;

  for (int i = tid; i < 64 * 65; i += 256) Sf[i] = 0.f;
  if (tid < 16) egc_l[tid] = egCg[tid * NBH + bh];

#define STG(DST, CC) do { \
    const ushort* ub = (const ushort*)SA + (size_t)((CC) * NBH + bh) * 24576; \
    _Pragma("unroll") \
    for (int j = 0; j < 8; ++j) { \
      const int g = j * 4 + w; \
      gload16(ub + g * 512 + lane * 8, &DST[g * 512]); \
    } \
    _Pragma("unroll") \
    for (int j = 8; j < 10; ++j) { \
      const int g = j * 4 + w; \
      gload16(ub + 16384 + H * 4096 + (g - 32) * 512 + lane * 8, &DST[g * 512]); \
    } \
  } while (0)

  STG(B0, 0);
  __syncthreads();   // prologue full drain: B0 ready

#define BODY(CURB, NXTB, CC) do { \
    if ((CC) + 1 < 16) STG(NXTB, (CC) + 1); \
    { const int v = tid >> 2, ds2 = tid & 3; \
      _Pragma("unroll") \
      for (int e = 0; e < 16; ++e) \
        Y2[v * 144 + ds2 * 16 + e] = (_Float16)Sf[v * 65 + ds2 * 16 + e]; } \
    if ((CC) + 1 < 16) asm volatile("s_waitcnt vmcnt(26) lgkmcnt(0)" ::: "memory"); \
    else               asm volatile("s_waitcnt vmcnt(16) lgkmcnt(0)" ::: "memory"); \
    __builtin_amdgcn_s_barrier(); \
    __builtin_amdgcn_sched_barrier(0); \
    /* b2: U = Z - W @ S0 -> Y2-right */ \
    { f32x4 accU[2][2]; \
      _Pragma("unroll") \
      for (int m = 0; m < 2; ++m) \
        _Pragma("unroll") \
        for (int n = 0; n < 2; ++n) \
          _Pragma("unroll") \
          for (int j = 0; j < 4; ++j) accU[m][n][j] = 0.f; \
      gemm64x(CURB, Y2, 144, wr, wc, lane, accU); \
      _Pragma("unroll") \
      for (int m = 0; m < 2; ++m) \
        _Pragma("unroll") \
        for (int n = 0; n < 2; ++n) \
          _Pragma("unroll") \
          for (int j = 0; j < 4; ++j) { \
            const int row = wr * 32 + m * 16 + (lane >> 4) * 4 + j; \
            const int col = wc * 32 + n * 16 + (lane & 15); \
            const float zv = h2f(CURB[16384 + SWZ(row, col)]); \
            Y2[col * 144 + 72 + row] = (_Float16)(zv - accU[m][n][j]); \
          } } \
    asm volatile("s_waitcnt lgkmcnt(0)" ::: "memory"); \
    __builtin_amdgcn_s_barrier(); \
    __builtin_amdgcn_sched_barrier(0); \
    /* b3: S update + O */ \
    { f32x4 accS[2][2], accO[2][2]; \
      _Pragma("unroll") \
      for (int m = 0; m < 2; ++m) \
        _Pragma("unroll") \
        for (int n = 0; n < 2; ++n) \
          _Pragma("unroll") \
          for (int j = 0; j < 4; ++j) { accS[m][n][j] = 0.f; accO[m][n][j] = 0.f; } \
      gemm64x(CURB + 12288, Y2 + 72, 144, wr, wc, lane, accS); \
      gemm64x(CURB + 8192,  Y2,      144, wr, wc, lane, accO); \
      gemm64x(CURB + 4096,  Y2 + 72, 144, wr, wc, lane, accO); \
      const float egC = egc_l[(CC)]; \
      _Pragma("unroll") \
      for (int m = 0; m < 2; ++m) \
        _Pragma("unroll") \
        for (int n = 0; n < 2; ++n) \
          _Pragma("unroll") \
          for (int j = 0; j < 4; ++j) { \
            const int row = wr * 32 + m * 16 + (lane >> 4) * 4 + j; \
            const int col = wc * 32 + n * 16 + (lane & 15); \
            Sf[col * 65 + row] = egC * Sf[col * 65 + row] + accS[m][n][j]; \
            o[(((size_t)b * TT + (CC) * 64 + row) * HH + h) * 128 + H * 64 + col] = accO[m][n][j]; \
          } } \
    asm volatile("s_waitcnt lgkmcnt(0)" ::: "memory"); \
    __builtin_amdgcn_s_barrier(); \
    __builtin_amdgcn_sched_barrier(0); \
  } while (0)

  for (int cp = 0; cp < 8; ++cp) {
    BODY(B0, B1, 2 * cp);
    BODY(B1, B0, 2 * cp + 1);
  }
#undef STG
#undef BODY
}

// ---------------------------------------------------------------------------
// RMS norm over 128 + SiLU gate; reads f16 g16; emits fp16 for final GEMM.
// ---------------------------------------------------------------------------
__global__ void rmsgate_kernel(const float* __restrict__ o, const ushort* __restrict__ g16,
                               ushort* __restrict__ gof)
{
  int gid  = blockIdx.x * blockDim.x + threadIdx.x;
  int wid  = gid >> 6;
  int lane = threadIdx.x & 63;
  if (wid >= BB * TT * HH) return;
  int h = wid % HH;
  int m = wid / HH;
  const float* orow = o + (size_t)wid * 128;
  float2 ov = *(const float2*)(orow + lane * 2);
  float ss = ov.x * ov.x + ov.y * ov.y;
#pragma unroll
  for (int mm = 32; mm >= 1; mm >>= 1) ss += __shfl_xor(ss, mm, 64);
  float scale = rsqrtf(ss * (1.f / 128.f) + EPSF);
  const ushort* gr = g16 + (size_t)m * TVv + h * 128 + lane * 2;
  float o0 = ov.x * scale * siluf(h2f(gr[0]));
  float o1 = ov.y * scale * siluf(h2f(gr[1]));
  *(uint*)(gof + (size_t)m * TVv + h * 128 + lane * 2) = pk2h(o0, o1);
}

// ---------------------------------------------------------------------------
extern "C" void kernel_launch(void* const* d_in, const int* in_sizes, int n_in,
                              void* d_out, int out_size, void* d_ws, size_t ws_size,
                              hipStream_t stream) {
  (void)in_sizes; (void)n_in; (void)out_size; (void)ws_size;
  const float* x       = (const float*)d_in[0];
  const float* w_q     = (const float*)d_in[1];
  const float* w_k     = (const float*)d_in[2];
  const float* w_v     = (const float*)d_in[3];
  const float* w_a     = (const float*)d_in[4];
  const float* w_b     = (const float*)d_in[5];
  const float* w_g     = (const float*)d_in[6];
  const float* w_out   = (const float*)d_in[7];
  const float* A_log   = (const float*)d_in[8];
  const float* dt_bias = (const float*)d_in[9];
  const float* qcw     = (const float*)d_in[10];
  const float* kcw     = (const float*)d_in[11];
  const float* vcw     = (const float*)d_in[12];

  float* ws  = (float*)d_ws;
  float* abi = ws + 15728640;

  ushort* xf    = (ushort*)(ws + 9437184);
  ushort* wcat  = (ushort*)(ws + 9437184 + 1572864);

  ushort* pA = (ushort*)ws;
  ushort* pB = (ushort*)(ws + 4718592);

  ushort* qc16 = (ushort*)(ws + 9437184);
  ushort* kc16 = (ushort*)(ws + 9437184 + 786432);
  ushort* vc16 = (ushort*)(ws + 9437184 + 1572864);
  ushort* g16  = (ushort*)(ws + 9437184 + 3145728);
  ushort* gof  = (ushort*)(ws + 9437184 + 4718592);

  _Float16* SA   = (_Float16*)ws;
  float*    egCg = ws + 4718592;
  float*    o    = ws + 4719104;
  ushort*   woutf = (ushort*)(ws + 7864832);
  ushort*   fp4   = (ushort*)ws;

  const int M = BB * TT;  // 2048
  dim3 blk(256);

  // 1) fp16 casts
  cast_f16_kernel<<<1536, blk, 0, stream>>>(x, xf);
  cast_w4_kernel<<<3456, blk, 0, stream>>>(w_q, w_k, w_v, w_g, wcat);

  // 2) fused qkv+g projection, K-split-2
  gemm_f16_ks<<<dim3(NQKVG / 128, M / 128, 2), blk, 0, stream>>>(
      xf, wcat, pA, M, NQKVG, DD, DD / 2);

  // 3) gating coefficients
  gate_kernel<<<M, blk, 0, stream>>>(x, w_a, w_b, A_log, dt_bias, abi);

  // 4) conv + SiLU + L2 norm
  conv_silu_kernel<<<24576, blk, 0, stream>>>(pA, pB, qcw, kcw, vcw, qc16, kc16, vc16);

  // 5) fold g-columns of partials -> g16
  gsum16_kernel<<<1536, blk, 0, stream>>>(pA, pB, g16);

  // 6) scan
  scan_phaseA<<<16 * NBH, blk, 0, stream>>>(qc16, kc16, vc16, abi, SA, egCg);
  scan_phaseB<<<2 * NBH, blk, 0, stream>>>(SA, egCg, o);

  // 7) cast w_out
  cast_f16_kernel<<<1152, blk, 0, stream>>>(w_out, woutf);

  // 8) RMS norm + SiLU gate
  rmsgate_kernel<<<6144, blk, 0, stream>>>(o, g16, gof);

  // 9) output projection, K-split-4
  gemm_f16_ks<<<dim3(TVv / 128, M / 128, 4), blk, 0, stream>>>(
      gof, woutf, fp4, M, TVv, DD, DD / 4);

  // 10) reduce partials
  reduce4_kernel<<<1536, blk, 0, stream>>>(fp4, (float*)d_out);
}

// Round 24
// 206.946 us; speedup vs baseline: 1.2382x; 1.0348x over previous
//
#include <hip/hip_runtime.h>
#include <math.h>

#define BB 2
#define TT 1024
#define DD 1536
#define HH 12
#define TQK 768
#define TVv 1536
#define CQKV 3072
#define NQKVG 4608
#define EPSF 1e-6f
#define NBH (BB * HH)   // 24

// scratch swizzle: row-linear, 16B chunks XOR'd by row&7 (conflict-free b128)
#define SWZ(row, col) ((row) * 64 + ((((col) >> 3) ^ ((row) & 7)) << 3) + ((col) & 7))

typedef __attribute__((ext_vector_type(8))) _Float16 half8v;
typedef __attribute__((ext_vector_type(4))) float f32x4;

__device__ __forceinline__ float siluf(float x) { return x / (1.f + expf(-x)); }

__device__ __forceinline__ uint pk2h(float a, float b) {
  union { _Float16 h[2]; uint u; } p;
  p.h[0] = (_Float16)a; p.h[1] = (_Float16)b;
  return p.u;
}
__device__ __forceinline__ ushort f2h(float f) {
  _Float16 h = (_Float16)f; ushort u; __builtin_memcpy(&u, &h, 2); return u;
}
__device__ __forceinline__ float h2f(ushort u) {
  _Float16 h; __builtin_memcpy(&h, &u, 2); return (float)h;
}

// async global->LDS
__device__ __forceinline__ void gload16(const void* g, void* l) {
  __builtin_amdgcn_global_load_lds(
      (const __attribute__((address_space(1))) void*)g,
      (__attribute__((address_space(3))) void*)l, 16, 0, 0);
}

// ---------------------------------------------------------------------------
// fp16 MFMA GEMM, K-split, COMPILE-TIME K/KS/Z (full unroll -> immediate
// global offsets, minimal addr VALU) + bijective XCD swizzle (grid%8==0),
// col-tile-major work order so each XCD chunk shares B-panels.
// 1D grid: nwg = (M/128)*(N/128)*Z.
// ---------------------------------------------------------------------------
template <int K, int KS, int Z>
__global__ __launch_bounds__(256) void gemm_f16_ks(
    const ushort* __restrict__ X, const ushort* __restrict__ W,
    ushort* __restrict__ P, int M, int N)
{
  __shared__ ushort Ah[128 * 64];
  __shared__ ushort Bh[128 * 64];
  const int tid  = threadIdx.x;
  const int lane = tid & 63;
  const int w    = tid >> 6;
  const int wr   = w >> 1, wc = w & 1;

  // bijective XCD swizzle (hardware block i -> work item wk)
  const int nwg = gridDim.x;
  const int i0  = blockIdx.x;
  const int wk  = (i0 & 7) * (nwg >> 3) + (i0 >> 3);
  const int ncz = (M >> 7) * Z;          // per-col-tile count
  const int bx  = wk / ncz;
  const int rem = wk % ncz;
  const int by  = rem / Z;
  const int z   = rem % Z;

  const int r0  = by * 128, c0 = bx * 128;
  const int k0b = z * KS;
  ushort* Pz = P + (size_t)z * M * N;

  const int dr   = lane >> 3;
  const int slot = (lane & 7) ^ dr;

  f32x4 acc[4][4];
#pragma unroll
  for (int m = 0; m < 4; ++m)
#pragma unroll
    for (int n = 0; n < 4; ++n)
#pragma unroll
      for (int j = 0; j < 4; ++j) acc[m][n][j] = 0.f;

#pragma unroll
  for (int ki = 0; ki < KS / 64; ++ki) {
    const int k0 = k0b + ki * 64;
#pragma unroll
    for (int j = 0; j < 4; ++j) {
      const int row  = (w * 4 + j) * 8 + dr;
      const size_t xo = (size_t)(r0 + row) * K + k0 + slot * 8;
      const size_t wo = (size_t)(c0 + row) * K + k0 + slot * 8;
      const int ldso = (w * 4 + j) * 512;
      gload16(X + xo, Ah + ldso);
      gload16(W + wo, Bh + ldso);
    }
    __syncthreads();
#pragma unroll
    for (int kk = 0; kk < 2; ++kk) {
      const int kc8 = kk * 4 + (lane >> 4);
      const int sw  = (kc8 ^ (lane & 7)) << 3;
      half8v a[4], b[4];
#pragma unroll
      for (int m = 0; m < 4; ++m)
        a[m] = *(const half8v*)(Ah + (wr * 64 + m * 16 + (lane & 15)) * 64 + sw);
#pragma unroll
      for (int n = 0; n < 4; ++n)
        b[n] = *(const half8v*)(Bh + (wc * 64 + n * 16 + (lane & 15)) * 64 + sw);
#pragma unroll
      for (int m = 0; m < 4; ++m)
#pragma unroll
        for (int n = 0; n < 4; ++n)
          acc[m][n] = __builtin_amdgcn_mfma_f32_16x16x32_f16(a[m], b[n], acc[m][n], 0, 0, 0);
    }
    __syncthreads();
  }

  const int crow = (lane >> 4) * 4;
  const int ccol = lane & 15;
#pragma unroll
  for (int m = 0; m < 4; ++m)
#pragma unroll
    for (int j = 0; j < 4; ++j) {
      ushort* cp = Pz + (size_t)(r0 + wr * 64 + m * 16 + crow + j) * N + c0 + wc * 64 + ccol;
#pragma unroll
      for (int n = 0; n < 4; ++n) cp[n * 16] = f2h(acc[m][n][j]);
    }
}

// ---------------------------------------------------------------------------
// f32 -> fp16 casts.
// ---------------------------------------------------------------------------
__device__ __forceinline__ void cast8_store(const float* f, ushort* dst, size_t e)
{
  uint4 pk;
  pk.x = pk2h(f[0], f[1]); pk.y = pk2h(f[2], f[3]);
  pk.z = pk2h(f[4], f[5]); pk.w = pk2h(f[6], f[7]);
  *(uint4*)(dst + e) = pk;
}

__global__ void cast_f16_kernel(const float* __restrict__ src, ushort* __restrict__ dst)
{
  int cid = blockIdx.x * blockDim.x + threadIdx.x;
  size_t e = (size_t)cid * 8;
  float f[8];
  *(float4*)(f)     = *(const float4*)(src + e);
  *(float4*)(f + 4) = *(const float4*)(src + e + 4);
  cast8_store(f, dst, e);
}

__global__ void cast_w4_kernel(const float* __restrict__ wq, const float* __restrict__ wk,
                               const float* __restrict__ wv, const float* __restrict__ wg,
                               ushort* __restrict__ dst)
{
  int cid = blockIdx.x * blockDim.x + threadIdx.x;
  size_t e = (size_t)cid * 8;
  const float* src; size_t off;
  if (e < 1179648)      { src = wq; off = e; }
  else if (e < 2359296) { src = wk; off = e - 1179648; }
  else if (e < 4718592) { src = wv; off = e - 2359296; }
  else                  { src = wg; off = e - 4718592; }
  float f[8];
  *(float4*)(f)     = *(const float4*)(src + off);
  *(float4*)(f + 4) = *(const float4*)(src + off + 4);
  cast8_store(f, dst, e);
}

// ---------------------------------------------------------------------------
// Causal depthwise conv (K=4) + SiLU + fused L2-norm + FUSED g-fold:
// grid covers all 4608 cols; cols >= 3072 take the add-only path into g16.
// ---------------------------------------------------------------------------
__global__ void conv_silu_kernel(
    const ushort* __restrict__ pA, const ushort* __restrict__ pB,
    const float* __restrict__ qw, const float* __restrict__ kw, const float* __restrict__ vw,
    ushort* __restrict__ qc, ushort* __restrict__ kc, ushort* __restrict__ vc,
    ushort* __restrict__ g16)
{
  int idx = blockIdx.x * blockDim.x + threadIdx.x;
  int c  = idx % NQKVG;
  int bt = idx / NQKVG;
  int t  = bt % TT;
  int b  = bt / TT;

  if (c >= CQKV) {   // g column: just fold the two partials (wave-uniform branch)
    size_t ii = (size_t)(b * TT + t) * NQKVG + c;
    g16[(size_t)(b * TT + t) * TVv + (c - CQKV)] = f2h(h2f(pA[ii]) + h2f(pB[ii]));
    return;
  }

  const float* wp;
  if (c < TQK)          wp = qw + (size_t)c * 4;
  else if (c < 2 * TQK) wp = kw + (size_t)(c - TQK) * 4;
  else                  wp = vw + (size_t)(c - 2 * TQK) * 4;

  float s = 0.f;
#pragma unroll
  for (int j = 0; j < 4; ++j) {
    int ts = t - 3 + j;
    if (ts >= 0) {
      size_t ii = (size_t)(b * TT + ts) * NQKVG + c;
      float v = h2f(pA[ii]) + h2f(pB[ii]);
      s = fmaf(v, wp[j], s);
    }
  }
  s = siluf(s);

  if (c < 2 * TQK) {
    float ss = s * s;
#pragma unroll
    for (int m = 32; m >= 1; m >>= 1) ss += __shfl_xor(ss, m, 64);
    s = s / fmaxf(sqrtf(ss), EPSF);
  }

  if (c < TQK) {
    int h = c >> 6, d = c & 63;
    qc[((size_t)(b * HH + h) * TT + t) * 64 + d] = f2h(s);
  } else if (c < 2 * TQK) {
    int c2 = c - TQK; int h = c2 >> 6, d = c2 & 63;
    kc[((size_t)(b * HH + h) * TT + t) * 64 + d] = f2h(s);
  } else {
    int c2 = c - 2 * TQK; int h = c2 >> 7, d = c2 & 127;
    vc[((size_t)(b * HH + h) * TT + t) * 128 + d] = f2h(s);
  }
}

// ---------------------------------------------------------------------------
// reduce4: d_out = sum of 4 f16 partials of the final GEMM.
// ---------------------------------------------------------------------------
__global__ void reduce4_kernel(const ushort* __restrict__ p, float* __restrict__ out)
{
  int cid = blockIdx.x * blockDim.x + threadIdx.x;
  size_t e = (size_t)cid * 8;
  float acc8[8];
#pragma unroll
  for (int i = 0; i < 8; ++i) acc8[i] = 0.f;
#pragma unroll
  for (int part = 0; part < 4; ++part) {
    half8v v = *(const half8v*)(p + (size_t)part * 3145728 + e);
#pragma unroll
    for (int i = 0; i < 8; ++i) acc8[i] += (float)v[i];
  }
  *(float4*)(out + e)     = make_float4(acc8[0], acc8[1], acc8[2], acc8[3]);
  *(float4*)(out + e + 4) = make_float4(acc8[4], acc8[5], acc8[6], acc8[7]);
}

// ---------------------------------------------------------------------------
// Gating: block per row; x row staged in LDS ONCE (was read by all 4 waves).
// ---------------------------------------------------------------------------
__global__ __launch_bounds__(256) void gate_kernel(
    const float* __restrict__ x, const float* __restrict__ w_a, const float* __restrict__ w_b,
    const float* __restrict__ A_log, const float* __restrict__ dt_bias,
    float* __restrict__ abi)
{
  __shared__ float xs[DD];
  const int m    = blockIdx.x;
  const int w    = threadIdx.x >> 6;
  const int lane = threadIdx.x & 63;
  const float* xr = x + (size_t)m * DD;
  for (int i = threadIdx.x; i < DD; i += 256) xs[i] = xr[i];
  __syncthreads();
  float xv[24];
#pragma unroll
  for (int i = 0; i < 24; ++i) xv[i] = xs[lane + i * 64];
  const int b = m / TT, t = m % TT;
#pragma unroll
  for (int j = 0; j < 6; ++j) {
    int o = w * 6 + j;
    bool isA = o < HH;
    int h = isA ? o : o - HH;
    const float* wr = (isA ? w_a : w_b) + (size_t)h * DD;
    float s = 0.f;
#pragma unroll
    for (int i = 0; i < 24; ++i) s = fmaf(xv[i], wr[lane + i * 64], s);
#pragma unroll
    for (int mm = 32; mm >= 1; mm >>= 1) s += __shfl_xor(s, mm, 64);
    if (lane == 0) {
      size_t idx = ((size_t)(b * HH + h) * TT + t) * 2;
      if (isA) {
        float a  = s + dt_bias[h];
        float sp = (a > 20.f) ? a : log1pf(expf(a));
        abi[idx] = expf(-expf(A_log[h]) * sp);
      } else {
        abi[idx + 1] = 2.f / (1.f + expf(-s));
      }
    }
  }
}

// ---------------------------------------------------------------------------
// Shared 64x64 MFMA GEMM helper (stride-padded LDS): C = X @ Y^T.
// ---------------------------------------------------------------------------
__device__ __forceinline__ void gemm64(
    const _Float16* XB, int xstr, const _Float16* YB, int ystr,
    int wr, int wc, int lane, int ksteps, int kpad, f32x4 acc[2][2])
{
#pragma unroll
  for (int m = 0; m < 2; ++m)
#pragma unroll
    for (int n = 0; n < 2; ++n)
#pragma unroll
      for (int j = 0; j < 4; ++j) acc[m][n][j] = 0.f;
#pragma unroll 4
  for (int kk = 0; kk < ksteps; ++kk) {
    const int koff = kk * 32 + ((kk >> 1) ? kpad : 0) + (lane >> 4) * 8;
    half8v a[2], b[2];
#pragma unroll
    for (int m = 0; m < 2; ++m)
      a[m] = *(const half8v*)(XB + (wr * 32 + m * 16 + (lane & 15)) * xstr + koff);
#pragma unroll
    for (int n = 0; n < 2; ++n)
      b[n] = *(const half8v*)(YB + (wc * 32 + n * 16 + (lane & 15)) * ystr + koff);
#pragma unroll
    for (int m = 0; m < 2; ++m)
#pragma unroll
      for (int n = 0; n < 2; ++n)
        acc[m][n] = __builtin_amdgcn_mfma_f32_16x16x32_f16(a[m], b[n], acc[m][n], 0, 0, 0);
  }
}

// Swizzled-X variant (stride-64 XOR layout). ACCUMULATES into acc.
__device__ __forceinline__ void gemm64x(
    const ushort* XB, const _Float16* YB, int ystr,
    int wr, int wc, int lane, f32x4 acc[2][2])
{
#pragma unroll
  for (int kk = 0; kk < 2; ++kk) {
    const int cl = kk * 4 + (lane >> 4);
    half8v a[2], b[2];
#pragma unroll
    for (int m = 0; m < 2; ++m) {
      const int row = wr * 32 + m * 16 + (lane & 15);
      a[m] = *(const half8v*)((const _Float16*)XB + row * 64 + ((cl ^ (row & 7)) << 3));
    }
#pragma unroll
    for (int n = 0; n < 2; ++n)
      b[n] = *(const half8v*)(YB + (wc * 32 + n * 16 + (lane & 15)) * ystr + kk * 32 + (lane >> 4) * 8);
#pragma unroll
    for (int m = 0; m < 2; ++m)
#pragma unroll
      for (int n = 0; n < 2; ++n)
        acc[m][n] = __builtin_amdgcn_mfma_f32_16x16x32_f16(a[m], b[n], acc[m][n], 0, 0, 0);
  }
}

// ---------------------------------------------------------------------------
// Scan phase A (chunk-parallel, 384 blocks); SWZ scratch layout.
// ---------------------------------------------------------------------------
__global__ __launch_bounds__(256) void scan_phaseA(
    const ushort* __restrict__ qc, const ushort* __restrict__ kc,
    const ushort* __restrict__ vc, const float* __restrict__ abi,
    _Float16* __restrict__ SA, float* __restrict__ egCg)
{
  __shared__ _Float16 Kf[64 * 72];      // aliased as Tf after ph2
  __shared__ _Float16 Qf[64 * 72];
  __shared__ _Float16 KbT[64 * 72];
  __shared__ _Float16 VT[128 * 72];
  __shared__ float    Af[64 * 67];
  __shared__ float    Tg[64 * 67];
  __shared__ float    tmpf[1088];
  __shared__ float    g_s[64], bet_s[64], betg_s[64], eg_s[64], eKs_s[64];
  _Float16* Tf = Kf;

  const int unit = blockIdx.x;
  const int bh   = unit % NBH;
  const int c    = unit / NBH;
  const int c0   = c * 64;
  const int tid  = threadIdx.x;
  const int lane = tid & 63;
  const int w    = tid >> 6;
  const int wr   = w >> 1, wc = w & 1;

  _Float16* SAu = SA + (size_t)unit * 24576;

  if (tid < 64) {
    float2 ab = *(const float2*)(abi + ((size_t)bh * TT + c0 + tid) * 2);
    float gg = logf(ab.x);
#pragma unroll
    for (int off = 1; off < 64; off <<= 1) {
      float up = __shfl_up(gg, off, 64);
      if (tid >= off) gg += up;
    }
    float gC = __shfl(gg, 63, 64);
    g_s[tid]    = gg;
    bet_s[tid]  = ab.y;
    betg_s[tid] = ab.y * expf(gg);
    eg_s[tid]   = expf(gg);
    eKs_s[tid]  = expf(gC - gg);
    if (tid == 0) egCg[unit] = expf(gC);
  }
  __syncthreads();

  // ph1
  {
    const int t  = tid >> 2;
    const int dg = tid & 3;
    const ushort* krow = kc + ((size_t)bh * TT + c0 + t) * 64 + dg * 16;
    const ushort* qrow = qc + ((size_t)bh * TT + c0 + t) * 64 + dg * 16;
    const float bg = betg_s[t], egt = eg_s[t], ekt = eKs_s[t];
    half8v kva = *(const half8v*)(krow), kvb = *(const half8v*)(krow + 8);
    half8v qva = *(const half8v*)(qrow), qvb = *(const half8v*)(qrow + 8);
#pragma unroll
    for (int e = 0; e < 8; ++e) {
      const int d = dg * 16 + e;
      const float kf = (float)kva[e], qf = (float)qva[e];
      Kf[t * 72 + d]              = kva[e];
      KbT[d * 72 + t]             = (_Float16)(kf * bg);
      Qf[t * 72 + d]              = qva[e];
      SAu[8192 + SWZ(t, d)]       = (_Float16)(qf * egt);
      SAu[12288 + SWZ(d, t)]      = (_Float16)(kf * ekt);
    }
#pragma unroll
    for (int e = 0; e < 8; ++e) {
      const int d = dg * 16 + 8 + e;
      const float kf = (float)kvb[e], qf = (float)qvb[e];
      Kf[t * 72 + d]              = kvb[e];
      KbT[d * 72 + t]             = (_Float16)(kf * bg);
      Qf[t * 72 + d]              = qvb[e];
      SAu[8192 + SWZ(t, d)]       = (_Float16)(qf * egt);
      SAu[12288 + SWZ(d, t)]      = (_Float16)(kf * ekt);
    }
    const ushort* vrow = vc + ((size_t)bh * TT + c0 + t) * 128 + dg * 32;
    half8v v0 = *(const half8v*)(vrow),      v1 = *(const half8v*)(vrow + 8);
    half8v v2 = *(const half8v*)(vrow + 16), v3 = *(const half8v*)(vrow + 24);
#pragma unroll
    for (int e = 0; e < 8; ++e) {
      VT[(dg * 32 + e) * 72 + t]      = v0[e];
      VT[(dg * 32 + 8 + e) * 72 + t]  = v1[e];
      VT[(dg * 32 + 16 + e) * 72 + t] = v2[e];
      VT[(dg * 32 + 24 + e) * 72 + t] = v3[e];
    }
    for (int i = tid; i < 64 * 67; i += 256) Tg[i] = 0.f;
  }
  __syncthreads();

  // ph2: A and P
  {
    f32x4 accA[2][2], accP[2][2];
    gemm64(Kf, 72, Kf, 72, wr, wc, lane, 2, 0, accA);
    gemm64(Qf, 72, Kf, 72, wr, wc, lane, 2, 0, accP);
#pragma unroll
    for (int m = 0; m < 2; ++m)
#pragma unroll
      for (int n = 0; n < 2; ++n)
#pragma unroll
        for (int j = 0; j < 4; ++j) {
          const int row = wr * 32 + m * 16 + (lane >> 4) * 4 + j;
          const int col = wc * 32 + n * 16 + (lane & 15);
          const float eg = expf(g_s[row] - g_s[col]);
          Af[row * 67 + col] = (col < row) ? bet_s[row] * eg * accA[m][n][j] : 0.f;
          SAu[4096 + SWZ(row, col)] =
              (col <= row) ? (_Float16)(eg * accP[m][n][j]) : (_Float16)0.f;
        }
  }
  __syncthreads();

  // ph3a
  if (lane < 16) {
    const int R = w * 16;
    Tg[R * 67 + R + lane] = (lane == 0) ? 1.f : 0.f;
    for (int t = 1; t < 16; ++t) {
      float s = 0.f;
      for (int i = 0; i < t; ++i)
        s = fmaf(Af[(R + t) * 67 + R + i], Tg[(R + i) * 67 + R + lane], s);
      Tg[(R + t) * 67 + R + lane] = ((lane == t) ? 1.f : 0.f) - s;
    }
  }
  __syncthreads();
  // ph3b-1
  {
    const int r = (tid >> 4) & 15, cx = tid & 15;
#pragma unroll
    for (int p = 0; p < 2; ++p) {
      float s = 0.f;
      for (int i = 0; i < 16; ++i)
        s = fmaf(Af[(p * 32 + 16 + r) * 67 + p * 32 + i],
                 Tg[(p * 32 + i) * 67 + p * 32 + cx], s);
      tmpf[p * 272 + r * 17 + cx] = s;
    }
  }
  __syncthreads();
  // ph3b-2
  {
    const int r = (tid >> 4) & 15, cx = tid & 15;
#pragma unroll
    for (int p = 0; p < 2; ++p) {
      float s = 0.f;
      for (int i = 0; i < 16; ++i)
        s = fmaf(Tg[(p * 32 + 16 + r) * 67 + p * 32 + 16 + i],
                 tmpf[p * 272 + i * 17 + cx], s);
      Tg[(p * 32 + 16 + r) * 67 + p * 32 + cx] = -s;
    }
  }
  __syncthreads();
  // ph3c-1
  {
#pragma unroll
    for (int rep = 0; rep < 4; ++rep) {
      const int idx = tid + rep * 256;
      const int r = idx >> 5, cx = idx & 31;
      float s = 0.f;
      for (int i = 0; i < 32; ++i)
        s = fmaf(Af[(32 + r) * 67 + i], Tg[i * 67 + cx], s);
      tmpf[r * 33 + cx] = s;
    }
  }
  __syncthreads();
  // ph3c-2
  {
#pragma unroll
    for (int rep = 0; rep < 4; ++rep) {
      const int idx = tid + rep * 256;
      const int r = idx >> 5, cx = idx & 31;
      float s = 0.f;
      for (int i = 0; i < 32; ++i)
        s = fmaf(Tg[(32 + r) * 67 + 32 + i], tmpf[i * 33 + cx], s);
      Tg[(32 + r) * 67 + cx] = -s;
    }
  }
  __syncthreads();

  // ph4: cast Tg -> Tf
  {
    const int t = tid >> 2, qg = tid & 3;
#pragma unroll
    for (int e = 0; e < 16; ++e) {
      const int i = qg * 16 + e;
      Tf[t * 72 + i] = (_Float16)Tg[t * 67 + i];
    }
  }
  __syncthreads();

  // ph5: W, Z -> scratch (SWZ layout)
  {
    f32x4 accW[2][2];
    gemm64(Tf, 72, KbT, 72, wr, wc, lane, 2, 0, accW);
#pragma unroll
    for (int m = 0; m < 2; ++m)
#pragma unroll
      for (int n = 0; n < 2; ++n)
#pragma unroll
        for (int j = 0; j < 4; ++j) {
          const int row = wr * 32 + m * 16 + (lane >> 4) * 4 + j;
          const int col = wc * 32 + n * 16 + (lane & 15);
          SAu[SWZ(row, col)] = (_Float16)accW[m][n][j];
        }
#pragma unroll
    for (int H = 0; H < 2; ++H) {
      f32x4 accZ[2][2];
      gemm64(Tf, 72, VT + H * 64 * 72, 72, wr, wc, lane, 2, 0, accZ);
#pragma unroll
      for (int m = 0; m < 2; ++m)
#pragma unroll
        for (int n = 0; n < 2; ++n)
#pragma unroll
          for (int j = 0; j < 4; ++j) {
            const int row = wr * 32 + m * 16 + (lane >> 4) * 4 + j;
            const int col = wc * 32 + n * 16 + (lane & 15);
            SAu[16384 + H * 4096 + SWZ(row, col)] = (_Float16)accZ[m][n][j];
          }
    }
  }
}

// ---------------------------------------------------------------------------
// Scan phase B (R23-proven): gload_lds double-buffer, counted vmcnt.
// ---------------------------------------------------------------------------
__global__ __launch_bounds__(256) void scan_phaseB(
    const _Float16* __restrict__ SA, const float* __restrict__ egCg,
    float* __restrict__ o)
{
  __shared__ float    Sf[64 * 65];
  __shared__ ushort   B0[20480];
  __shared__ ushort   B1[20480];
  __shared__ _Float16 Y2[64 * 144];
  __shared__ float    egc_l[16];

  const int blk  = blockIdx.x;
  const int bh   = blk % NBH;
  const int H    = blk / NBH;
  const int b    = bh / HH, h = bh % HH;
  const int tid  = threadIdx.x;
  const int lane = tid & 63;
  const int w    = tid >> 6;
  const int wr   = w >> 1, wc = w & 1;

  for (int i = tid; i < 64 * 65; i += 256) Sf[i] = 0.f;
  if (tid < 16) egc_l[tid] = egCg[tid * NBH + bh];

#define STG(DST, CC) do { \
    const ushort* ub = (const ushort*)SA + (size_t)((CC) * NBH + bh) * 24576; \
    _Pragma("unroll") \
    for (int j = 0; j < 8; ++j) { \
      const int g = j * 4 + w; \
      gload16(ub + g * 512 + lane * 8, &DST[g * 512]); \
    } \
    _Pragma("unroll") \
    for (int j = 8; j < 10; ++j) { \
      const int g = j * 4 + w; \
      gload16(ub + 16384 + H * 4096 + (g - 32) * 512 + lane * 8, &DST[g * 512]); \
    } \
  } while (0)

  STG(B0, 0);
  __syncthreads();

#define BODY(CURB, NXTB, CC) do { \
    if ((CC) + 1 < 16) STG(NXTB, (CC) + 1); \
    { const int v = tid >> 2, ds2 = tid & 3; \
      _Pragma("unroll") \
      for (int e = 0; e < 16; ++e) \
        Y2[v * 144 + ds2 * 16 + e] = (_Float16)Sf[v * 65 + ds2 * 16 + e]; } \
    if ((CC) + 1 < 16) asm volatile("s_waitcnt vmcnt(26) lgkmcnt(0)" ::: "memory"); \
    else               asm volatile("s_waitcnt vmcnt(16) lgkmcnt(0)" ::: "memory"); \
    __builtin_amdgcn_s_barrier(); \
    __builtin_amdgcn_sched_barrier(0); \
    { f32x4 accU[2][2]; \
      _Pragma("unroll") \
      for (int m = 0; m < 2; ++m) \
        _Pragma("unroll") \
        for (int n = 0; n < 2; ++n) \
          _Pragma("unroll") \
          for (int j = 0; j < 4; ++j) accU[m][n][j] = 0.f; \
      gemm64x(CURB, Y2, 144, wr, wc, lane, accU); \
      _Pragma("unroll") \
      for (int m = 0; m < 2; ++m) \
        _Pragma("unroll") \
        for (int n = 0; n < 2; ++n) \
          _Pragma("unroll") \
          for (int j = 0; j < 4; ++j) { \
            const int row = wr * 32 + m * 16 + (lane >> 4) * 4 + j; \
            const int col = wc * 32 + n * 16 + (lane & 15); \
            const float zv = h2f(CURB[16384 + SWZ(row, col)]); \
            Y2[col * 144 + 72 + row] = (_Float16)(zv - accU[m][n][j]); \
          } } \
    asm volatile("s_waitcnt lgkmcnt(0)" ::: "memory"); \
    __builtin_amdgcn_s_barrier(); \
    __builtin_amdgcn_sched_barrier(0); \
    { f32x4 accS[2][2], accO[2][2]; \
      _Pragma("unroll") \
      for (int m = 0; m < 2; ++m) \
        _Pragma("unroll") \
        for (int n = 0; n < 2; ++n) \
          _Pragma("unroll") \
          for (int j = 0; j < 4; ++j) { accS[m][n][j] = 0.f; accO[m][n][j] = 0.f; } \
      gemm64x(CURB + 12288, Y2 + 72, 144, wr, wc, lane, accS); \
      gemm64x(CURB + 8192,  Y2,      144, wr, wc, lane, accO); \
      gemm64x(CURB + 4096,  Y2 + 72, 144, wr, wc, lane, accO); \
      const float egC = egc_l[(CC)]; \
      _Pragma("unroll") \
      for (int m = 0; m < 2; ++m) \
        _Pragma("unroll") \
        for (int n = 0; n < 2; ++n) \
          _Pragma("unroll") \
          for (int j = 0; j < 4; ++j) { \
            const int row = wr * 32 + m * 16 + (lane >> 4) * 4 + j; \
            const int col = wc * 32 + n * 16 + (lane & 15); \
            Sf[col * 65 + row] = egC * Sf[col * 65 + row] + accS[m][n][j]; \
            o[(((size_t)b * TT + (CC) * 64 + row) * HH + h) * 128 + H * 64 + col] = accO[m][n][j]; \
          } } \
    asm volatile("s_waitcnt lgkmcnt(0)" ::: "memory"); \
    __builtin_amdgcn_s_barrier(); \
    __builtin_amdgcn_sched_barrier(0); \
  } while (0)

  for (int cp = 0; cp < 8; ++cp) {
    BODY(B0, B1, 2 * cp);
    BODY(B1, B0, 2 * cp + 1);
  }
#undef STG
#undef BODY
}

// ---------------------------------------------------------------------------
// RMS norm over 128 + SiLU gate; reads f16 g16; emits fp16 for final GEMM.
// ---------------------------------------------------------------------------
__global__ void rmsgate_kernel(const float* __restrict__ o, const ushort* __restrict__ g16,
                               ushort* __restrict__ gof)
{
  int gid  = blockIdx.x * blockDim.x + threadIdx.x;
  int wid  = gid >> 6;
  int lane = threadIdx.x & 63;
  if (wid >= BB * TT * HH) return;
  int h = wid % HH;
  int m = wid / HH;
  const float* orow = o + (size_t)wid * 128;
  float2 ov = *(const float2*)(orow + lane * 2);
  float ss = ov.x * ov.x + ov.y * ov.y;
#pragma unroll
  for (int mm = 32; mm >= 1; mm >>= 1) ss += __shfl_xor(ss, mm, 64);
  float scale = rsqrtf(ss * (1.f / 128.f) + EPSF);
  const ushort* gr = g16 + (size_t)m * TVv + h * 128 + lane * 2;
  float o0 = ov.x * scale * siluf(h2f(gr[0]));
  float o1 = ov.y * scale * siluf(h2f(gr[1]));
  *(uint*)(gof + (size_t)m * TVv + h * 128 + lane * 2) = pk2h(o0, o1);
}

// ---------------------------------------------------------------------------
extern "C" void kernel_launch(void* const* d_in, const int* in_sizes, int n_in,
                              void* d_out, int out_size, void* d_ws, size_t ws_size,
                              hipStream_t stream) {
  (void)in_sizes; (void)n_in; (void)out_size; (void)ws_size;
  const float* x       = (const float*)d_in[0];
  const float* w_q     = (const float*)d_in[1];
  const float* w_k     = (const float*)d_in[2];
  const float* w_v     = (const float*)d_in[3];
  const float* w_a     = (const float*)d_in[4];
  const float* w_b     = (const float*)d_in[5];
  const float* w_g     = (const float*)d_in[6];
  const float* w_out   = (const float*)d_in[7];
  const float* A_log   = (const float*)d_in[8];
  const float* dt_bias = (const float*)d_in[9];
  const float* qcw     = (const float*)d_in[10];
  const float* kcw     = (const float*)d_in[11];
  const float* vcw     = (const float*)d_in[12];

  float* ws  = (float*)d_ws;
  float* abi = ws + 15728640;

  ushort* xf    = (ushort*)(ws + 9437184);
  ushort* wcat  = (ushort*)(ws + 9437184 + 1572864);

  ushort* pA = (ushort*)ws;
  ushort* pB = (ushort*)(ws + 4718592);

  ushort* qc16 = (ushort*)(ws + 9437184);
  ushort* kc16 = (ushort*)(ws + 9437184 + 786432);
  ushort* vc16 = (ushort*)(ws + 9437184 + 1572864);
  ushort* g16  = (ushort*)(ws + 9437184 + 3145728);
  ushort* gof  = (ushort*)(ws + 9437184 + 4718592);

  _Float16* SA   = (_Float16*)ws;
  float*    egCg = ws + 4718592;
  float*    o    = ws + 4719104;
  ushort*   woutf = (ushort*)(ws + 7864832);
  ushort*   fp4   = (ushort*)ws;

  const int M = BB * TT;  // 2048
  dim3 blk(256);

  // 1) fp16 casts
  cast_f16_kernel<<<1536, blk, 0, stream>>>(x, xf);
  cast_w4_kernel<<<3456, blk, 0, stream>>>(w_q, w_k, w_v, w_g, wcat);

  // 2) fused qkv+g projection, K-split-2 (compile-time dims, XCD swizzle)
  gemm_f16_ks<DD, DD / 2, 2><<<1152, blk, 0, stream>>>(xf, wcat, pA, M, NQKVG);

  // 3) gating coefficients
  gate_kernel<<<M, blk, 0, stream>>>(x, w_a, w_b, A_log, dt_bias, abi);

  // 4) conv + SiLU + L2 norm + fused g-fold (grid covers all 4608 cols)
  conv_silu_kernel<<<36864, blk, 0, stream>>>(pA, pB, qcw, kcw, vcw,
                                              qc16, kc16, vc16, g16);

  // 5) scan
  scan_phaseA<<<16 * NBH, blk, 0, stream>>>(qc16, kc16, vc16, abi, SA, egCg);
  scan_phaseB<<<2 * NBH, blk, 0, stream>>>(SA, egCg, o);

  // 6) cast w_out
  cast_f16_kernel<<<1152, blk, 0, stream>>>(w_out, woutf);

  // 7) RMS norm + SiLU gate
  rmsgate_kernel<<<6144, blk, 0, stream>>>(o, g16, gof);

  // 8) output projection, K-split-4 (compile-time dims, XCD swizzle)
  gemm_f16_ks<DD, DD / 4, 4><<<768, blk, 0, stream>>>(gof, woutf, fp4, M, TVv);

  // 9) reduce partials
  reduce4_kernel<<<1536, blk, 0, stream>>>(fp4, (float*)d_out);
}